// Round 17
// baseline (322.165 us; speedup 1.0000x reference)
//
#include <hip/hip_runtime.h>
#include <hip/hip_bf16.h>
#include <math.h>
#include <stdint.h>

namespace {

constexpr int B_ = 2, S_ = 2048, D_ = 512, H_ = 8, HD_ = 64, K_ = 31,
              FF_ = 2048, G_ = 4, E_ = 2;
constexpr int N_ = B_ * S_;
constexpr int SP_ = S_ + 30;   // padded rows per batch (15 zeros each side)
constexpr float EPS_ = 1e-6f;
constexpr int PADCAP_ = 4608;  // 4096 + 4*127 rounded up to 128-tiles

typedef __bf16 bf16x8 __attribute__((ext_vector_type(8)));
typedef unsigned short u16x8 __attribute__((ext_vector_type(8)));
typedef unsigned short u16x4 __attribute__((ext_vector_type(4)));
typedef float f32x4 __attribute__((ext_vector_type(4)));

__device__ __forceinline__ uint16_t f2bf(float f) {
  union { float f; uint32_t u; } v; v.f = f;
  uint32_t r = v.u + 0x7FFFu + ((v.u >> 16) & 1u);
  return (uint16_t)(r >> 16);
}
__device__ __forceinline__ float bf2f(uint16_t u) {
  union { uint32_t u; float f; } v; v.u = (uint32_t)u << 16;
  return v.f;
}

__device__ __forceinline__ float gelu_f(float x) {
  const float c = 0.7978845608028654f;  // sqrt(2/pi)
  return 0.5f * x * (1.0f + tanhf(c * (x + 0.044715f * x * x * x)));
}

#define GLOAD_LDS16(gsrc, ldst)                                              \
  __builtin_amdgcn_global_load_lds(                                          \
      (const __attribute__((address_space(1))) void*)(gsrc),                 \
      (__attribute__((address_space(3))) void*)(ldst), 16, 0, 0)

#define VMCNT(n) asm volatile("s_waitcnt vmcnt(" #n ")" ::: "memory")
#define MEMBAR asm volatile("" ::: "memory")
#define BARRIER __builtin_amdgcn_s_barrier()
#define PRIO1 __builtin_amdgcn_s_setprio(1)
#define PRIO0 __builtin_amdgcn_s_setprio(0)

// ---- swizzled-tile K-step: tiles are [rows][64 k] bf16, 128B rows,
// chunk c (16B) of row r lives at byte r*128 + (c ^ (r&7))*16.
__device__ __forceinline__ void kstep_swz(const char* As, const char* Bs,
                                          int wr, int wc, int l15, int g,
                                          f32x4 acc[4][4]) {
#pragma unroll
  for (int ks = 0; ks < 2; ++ks) {
    int co = (((ks << 2) | g) ^ (l15 & 7)) << 4;
    bf16x8 a[4], b[4];
#pragma unroll
    for (int m = 0; m < 4; ++m)
      a[m] = *(const bf16x8*)(As + (wr * 64 + m * 16 + l15) * 128 + co);
#pragma unroll
    for (int n = 0; n < 4; ++n)
      b[n] = *(const bf16x8*)(Bs + (wc * 64 + n * 16 + l15) * 128 + co);
    PRIO1;
#pragma unroll
    for (int m = 0; m < 4; ++m)
#pragma unroll
      for (int n = 0; n < 4; ++n)
        acc[m][n] = __builtin_amdgcn_mfma_f32_16x16x32_bf16(a[m], b[n], acc[m][n], 0, 0, 0);
    PRIO0;
  }
}

// Double-buffered BK=64 K-loop, swizzled tiles, counted vmcnt(8).
template <int NK>
__device__ __forceinline__ void gemm_k_dbuf64(const uint16_t* Ab, int lda,
                                              const uint16_t* Bb, int ldb,
                                              int t, int wr, int wc, int l15, int g,
                                              uint16_t (*As)[8192], uint16_t (*Bs)[8192],
                                              f32x4 acc[4][4]) {
  int r8 = t >> 3, clog = (t & 7) ^ (r8 & 7);
  int ubase = (t & ~63) * 8;
  auto stage = [&](int k0, int buf) {
#pragma unroll
    for (int pi = 0; pi < 4; ++pi) {
      int row = pi * 32 + r8;
      GLOAD_LDS16(Ab + (size_t)row * lda + k0 + clog * 8, As[buf] + pi * 2048 + ubase);
      GLOAD_LDS16(Bb + (size_t)row * ldb + k0 + clog * 8, Bs[buf] + pi * 2048 + ubase);
    }
  };
  stage(0, 0);
  int cur = 0;
  for (int ki = 0; ki < NK; ++ki) {
    if (ki + 1 < NK) {
      stage((ki + 1) * 64, cur ^ 1);
      VMCNT(8);
    } else {
      VMCNT(0);
    }
    BARRIER; MEMBAR;
    kstep_swz((const char*)As[cur], (const char*)Bs[cur], wr, wc, l15, g, acc);
    MEMBAR; BARRIER;
    cur ^= 1;
  }
}

// -------- fused prep: weight transposes + zero pad + bucket + LN1 -----------
__global__ __launch_bounds__(256) void prep_kernel(
    const float* __restrict__ ck, const float* __restrict__ wq,
    const float* __restrict__ wk, const float* __restrict__ wv,
    const float* __restrict__ wo, const float* __restrict__ w1,
    const float* __restrict__ w2, uint16_t* __restrict__ ckT,
    uint16_t* __restrict__ wqkvT, uint16_t* __restrict__ woT,
    uint16_t* __restrict__ w1T, uint16_t* __restrict__ w2T,
    uint16_t* __restrict__ Hpad, uint16_t* __restrict__ x2bf,
    const float* __restrict__ x, const float* __restrict__ ln1s,
    const float* __restrict__ ln1b, const int* __restrict__ gid,
    int* __restrict__ list, int* __restrict__ poff) {
  int bi = blockIdx.x, t = threadIdx.x;
  if (bi >= 25406) {  // ---- LN1 rows -> padded Hpad (bf16) ----
    int row = bi - 25406;
    const float* xr = x + (size_t)row * D_;
    float v0 = xr[t], v1 = xr[t + 256];
    float s = v0 + v1, sq = v0 * v0 + v1 * v1;
    for (int o = 32; o > 0; o >>= 1) {
      s += __shfl_down(s, o);
      sq += __shfl_down(sq, o);
    }
    __shared__ float sm[8];
    __shared__ float mr[2];
    int lane = t & 63, wid = t >> 6;
    if (lane == 0) { sm[wid] = s; sm[wid + 4] = sq; }
    __syncthreads();
    if (t == 0) {
      float ts = sm[0] + sm[1] + sm[2] + sm[3];
      float tq = sm[4] + sm[5] + sm[6] + sm[7];
      float m = ts / D_;
      mr[0] = m;
      mr[1] = rsqrtf(tq / D_ - m * m + EPS_);
    }
    __syncthreads();
    float m = mr[0], rs = mr[1];
    size_t drow = (size_t)(row >> 11) * SP_ + 15 + (row & 2047);
    uint16_t* orow = Hpad + drow * D_;
    orow[t] = f2bf((v0 - m) * rs * ln1s[t] + ln1b[t]);
    orow[t + 256] = f2bf((v1 - m) * rs * ln1s[t + 256] + ln1b[t + 256]);
    return;
  }
  if (bi == 25405) {  // ---- bucket (single block), groups padded to 128 ----
    __shared__ int cnt[G_], cur[G_];
    if (t < G_) cnt[t] = 0;
    __syncthreads();
    for (int i = t; i < N_; i += 256) atomicAdd(&cnt[gid[i]], 1);
    __syncthreads();
    if (t == 0) {
      int off = 0;
      for (int g = 0; g < G_; ++g) {
        poff[g] = off;
        cur[g] = off;
        off += (cnt[g] + 127) & ~127;
      }
      poff[G_] = off;
    }
    __syncthreads();
    for (int i = t; i < PADCAP_; i += 256) list[i] = N_;
    __syncthreads();
    for (int i = t; i < N_; i += 256) {
      int p = atomicAdd(&cur[gid[i]], 1);
      list[p] = i;
    }
    return;
  }
  if (bi >= 25344) {  // ---- zero-pad blocks ----
    int j4 = bi - 25344;
    uint16_t* dst;
    if (j4 < 60) {
      int b = j4 / 30, j = j4 % 30;
      int row = b * SP_ + (j < 15 ? j : 2048 + j);
      dst = Hpad + (size_t)row * D_;
    } else {
      dst = x2bf + (size_t)N_ * D_;
    }
    dst[t] = 0;
    dst[t + 256] = 0;
    return;
  }
  const float* src;
  uint16_t* dst;
  int R, C, r0, c0;
  if (bi < 7936) {
    int z = bi >> 8, tile = bi & 255;
    R = 512; C = 512;
    c0 = (tile & 15) * 32; r0 = (tile >> 4) * 32;
    src = ck + (size_t)z * 262144; dst = ckT + (size_t)z * 262144;
  } else if (bi < 8960) {
    int idx = bi - 7936, mat = idx >> 8, tile = idx & 255;
    R = 512; C = 512;
    c0 = (tile & 15) * 32; r0 = (tile >> 4) * 32;
    src = mat == 0 ? wq : (mat == 1 ? wk : (mat == 2 ? wv : wo));
    dst = mat == 3 ? woT : wqkvT + (size_t)mat * 262144;
  } else if (bi < 17152) {
    int idx = bi - 8960, z = idx >> 10, tile = idx & 1023;
    R = 512; C = 2048;
    c0 = (tile & 63) * 32; r0 = (tile >> 6) * 32;
    src = w1 + (size_t)z * 1048576; dst = w1T + (size_t)z * 1048576;
  } else {
    int idx = bi - 17152, z = idx >> 10, tile = idx & 1023;
    R = 2048; C = 512;
    c0 = (tile & 15) * 32; r0 = (tile >> 4) * 32;
    src = w2 + (size_t)z * 1048576; dst = w2T + (size_t)z * 1048576;
  }
  __shared__ float tile[32][33];
  int tc = t & 31, tr = t >> 5;
#pragma unroll
  for (int i = 0; i < 4; ++i) {
    int r = tr + i * 8;
    tile[r][tc] = src[(size_t)(r0 + r) * C + c0 + tc];
  }
  __syncthreads();
#pragma unroll
  for (int i = 0; i < 4; ++i) {
    int rr = tr + i * 8;
    dst[(size_t)(c0 + rr) * R + r0 + tc] = f2bf(tile[tc][rr]);
  }
}

// ---------------- conv: 256x256 block, 8 waves, faithful 4-phase schedule ---
__global__ __launch_bounds__(512) void conv_mfma_kernel(
    const uint16_t* __restrict__ Hpad, const uint16_t* __restrict__ ckT,
    uint16_t* __restrict__ Pout) {
  __shared__ __align__(16) uint16_t As[2][20480];
  __shared__ __align__(16) uint16_t Bs[2][16384];
  int bid = blockIdx.x;
  int ks = bid & 7, tmn = bid >> 3, tm = tmn & 15, tn = tmn >> 4;
  int t = threadIdx.x;
  int w = t >> 6, l = t & 63, l15 = l & 15, g = l >> 4;
  int wr = w >> 2, wc = w & 3;
  int row0 = tm * 256, b = row0 >> 11, s0 = row0 & 2047;
  int kb = ks * 4, ntap = (ks == 7) ? 3 : 4;
  const uint16_t* Abase = Hpad + (size_t)(b * SP_ + s0 + kb) * D_;
  int r8 = t >> 3, clog = (t & 7) ^ (r8 & 7);
  int ubase = (t & ~63) * 8;
  f32x4 acc[8][4] = {};

  auto stageA = [&](int d0, int buf) {
#pragma unroll
    for (int pi = 0; pi < 5; ++pi)
      GLOAD_LDS16(Abase + (size_t)(pi * 64 + r8) * D_ + d0 + clog * 8,
                  As[buf] + pi * 4096 + ubase);
  };
  auto stageB = [&](int k, int d0, int buf) {
    const uint16_t* Bk = ckT + (size_t)k * D_ * D_ + (size_t)(tn * 256) * D_;
#pragma unroll
    for (int pi = 0; pi < 4; ++pi)
      GLOAD_LDS16(Bk + (size_t)(pi * 64 + r8) * D_ + d0 + clog * 8,
                  Bs[buf] + pi * 4096 + ubase);
  };

  stageA(0, 0);
  stageB(kb, 0, 0);
  VMCNT(0);
  BARRIER; MEMBAR;

  int acur = 0, bcur = 0;
  for (int di = 0; di < 8; ++di) {
    int d0 = di * 64;
    for (int i = 0; i < ntap; ++i) {
      const char* Ac = (const char*)As[acur];
      const char* Bc = (const char*)Bs[bcur];
      bf16x8 a[4], bb[4];
      auto rdA = [&](int kkq, int mh) {
        int cA = (((kkq << 2) | g) ^ ((i + l15) & 7)) << 4;
#pragma unroll
        for (int mi = 0; mi < 4; ++mi)
          a[mi] = *(const bf16x8*)(Ac + (i + wr * 128 + (mh * 4 + mi) * 16 + l15) * 128 + cA);
      };
      auto rdB = [&](int kkq) {
        int cB = (((kkq << 2) | g) ^ (l15 & 7)) << 4;
#pragma unroll
        for (int n = 0; n < 4; ++n)
          bb[n] = *(const bf16x8*)(Bc + (wc * 64 + n * 16 + l15) * 128 + cB);
      };
      auto mma = [&](int mh) {
        PRIO1;
#pragma unroll
        for (int mi = 0; mi < 4; ++mi)
#pragma unroll
          for (int n = 0; n < 4; ++n)
            acc[mh * 4 + mi][n] = __builtin_amdgcn_mfma_f32_16x16x32_bf16(
                a[mi], bb[n], acc[mh * 4 + mi][n], 0, 0, 0);
        PRIO0;
      };
      // ---- phase 0: rd (mh0,kk0) pre-barrier, stage issue, barrier, MFMA --
      rdA(0, 0); rdB(0);
      MEMBAR;
      if (i + 1 < ntap) {
        stageB(kb + i + 1, d0, bcur ^ 1);
      } else if (di + 1 < 8) {
        stageA(d0 + 64, acur ^ 1);
        stageB(kb, d0 + 64, bcur ^ 1);
      }
      BARRIER;
      mma(0);
      MEMBAR; BARRIER;
      // ---- phase 1: (mh1,kk0), reuse bb ----
      rdA(0, 1);
      MEMBAR;
      BARRIER;
      mma(1);
      MEMBAR; BARRIER;
      // ---- phase 2: (mh0,kk1) ----
      rdA(1, 0); rdB(1);
      MEMBAR;
      BARRIER;
      mma(0);
      MEMBAR; BARRIER;
      // ---- phase 3: (mh1,kk1) + vmcnt for next tap's buffers ----
      rdA(1, 1);
      MEMBAR;
      VMCNT(0);
      BARRIER;
      mma(1);
      MEMBAR; BARRIER;
      bcur ^= 1;
    }
    acur ^= 1;
  }
  uint16_t* P = Pout + (size_t)ks * N_ * D_;
#pragma unroll
  for (int m = 0; m < 8; ++m) {
    int r = row0 + wr * 128 + m * 16 + g * 4;
#pragma unroll
    for (int n = 0; n < 4; ++n) {
      int c = tn * 256 + wc * 64 + n * 16 + l15;
#pragma unroll
      for (int j = 0; j < 4; ++j)
        P[(size_t)(r + j) * D_ + c] = f2bf(acc[m][n][j]);
    }
  }
}

// -------- conv epilogue + LN2 fused: one wave per token row ------------------
__global__ __launch_bounds__(256) void epi_ln_kernel(
    const uint16_t* __restrict__ P, const float* __restrict__ cb,
    const float* __restrict__ xres, const float* __restrict__ ln2s,
    const float* __restrict__ ln2b, float* __restrict__ x1,
    uint16_t* __restrict__ ln2bf) {
  int t = threadIdx.x;
  int row = blockIdx.x * 4 + (t >> 6);
  int l = t & 63, d0 = l * 8;
  size_t base = (size_t)row * D_ + d0;
  float v[8] = {};
#pragma unroll
  for (int q = 0; q < 8; ++q) {
    u16x8 pv = *(const u16x8*)(P + (size_t)q * N_ * D_ + base);
#pragma unroll
    for (int j = 0; j < 8; ++j) v[j] += bf2f(pv[j]);
  }
  float s = 0.f, sq = 0.f;
#pragma unroll
  for (int j = 0; j < 8; ++j) {
    float xv = xres[base + j];
    float vv = gelu_f(v[j] + cb[d0 + j]) + xv;
    v[j] = vv;
    s += vv;
    sq += vv * vv;
  }
  float4 o0 = {v[0], v[1], v[2], v[3]};
  float4 o1 = {v[4], v[5], v[6], v[7]};
  *(float4*)(x1 + base) = o0;
  *(float4*)(x1 + base + 4) = o1;
  for (int o = 1; o < 64; o <<= 1) {
    s += __shfl_xor(s, o);
    sq += __shfl_xor(sq, o);
  }
  float m = s / D_;
  float rs = rsqrtf(sq / D_ - m * m + EPS_);
  u16x8 ob;
#pragma unroll
  for (int j = 0; j < 8; ++j)
    ob[j] = f2bf((v[j] - m) * rs * ln2s[d0 + j] + ln2b[d0 + j]);
  *(u16x8*)(ln2bf + base) = ob;
}

// ------- fused QKV GEMM -> bf16 Q(scaled log2e/8), K row-major, V^T ---------
__global__ __launch_bounds__(256) void gemm_qkv_kernel(
    const uint16_t* __restrict__ A, const uint16_t* __restrict__ BT,
    const float* __restrict__ bq, const float* __restrict__ bk,
    const float* __restrict__ bv, uint16_t* __restrict__ Qb,
    uint16_t* __restrict__ Kb, uint16_t* __restrict__ VT) {
  __shared__ __align__(16) uint16_t As[2][8192], Bs[2][8192];
  int tm = blockIdx.x, tn = blockIdx.y;
  int t = threadIdx.x;
  int w = t >> 6, l = t & 63, l15 = l & 15, g = l >> 4;
  int wr = w >> 1, wc = w & 1;
  int row0 = tm * 128;
  f32x4 acc[4][4] = {};
  gemm_k_dbuf64<8>(A + (size_t)row0 * D_, D_, BT + (size_t)(tn * 128) * D_, D_,
                   t, wr, wc, l15, g, As, Bs, acc);
  int sel = tn >> 2, col0 = (tn & 3) * 128;
  if (sel < 2) {
    uint16_t* dst = sel == 0 ? Qb : Kb;
    const float* bias = sel == 0 ? bq : bk;
    float scl = sel == 0 ? 0.18033688f : 1.0f;  // (1/8) * log2(e) for exp2 softmax
#pragma unroll
    for (int m = 0; m < 4; ++m) {
      int r = row0 + wr * 64 + m * 16 + g * 4;
#pragma unroll
      for (int n = 0; n < 4; ++n) {
        int c = col0 + wc * 64 + n * 16 + l15;
#pragma unroll
        for (int j = 0; j < 4; ++j)
          dst[(size_t)(r + j) * D_ + c] = f2bf((acc[m][n][j] + bias[c]) * scl);
      }
    }
  } else {
    // V: store transposed [b][h][d][s] for direct attn staging
#pragma unroll
    for (int m = 0; m < 4; ++m) {
      int tb = row0 + wr * 64 + m * 16 + g * 4;
      int b = tb >> 11, s = tb & 2047;
#pragma unroll
      for (int n = 0; n < 4; ++n) {
        int c = col0 + wc * 64 + n * 16 + l15;
        int hh = c >> 6, d = c & 63;
        u16x4 pack;
#pragma unroll
        for (int j = 0; j < 4; ++j) pack[j] = f2bf(acc[m][n][j] + bv[c]);
        *(u16x4*)(VT + ((size_t)((b * H_ + hh) * HD_ + d) * S_ + s)) = pack;
      }
    }
  }
}

// ---------------- WO GEMM + bias + residual -> out (f32) + x2 (bf16) --------
__global__ __launch_bounds__(256) void gemm_wo_kernel(
    const uint16_t* __restrict__ A, const uint16_t* __restrict__ BT,
    const float* __restrict__ bo, const float* __restrict__ res,
    float* __restrict__ out, uint16_t* __restrict__ x2bf) {
  __shared__ __align__(16) uint16_t As[2][8192], Bs[2][8192];
  int tm = blockIdx.x, tn = blockIdx.y;
  int t = threadIdx.x;
  int w = t >> 6, l = t & 63, l15 = l & 15, g = l >> 4;
  int wr = w >> 1, wc = w & 1;
  int row0 = tm * 128;
  f32x4 acc[4][4] = {};
  gemm_k_dbuf64<8>(A + (size_t)row0 * D_, D_, BT + (size_t)(tn * 128) * D_, D_,
                   t, wr, wc, l15, g, As, Bs, acc);
#pragma unroll
  for (int m = 0; m < 4; ++m) {
    int r = row0 + wr * 64 + m * 16 + g * 4;
#pragma unroll
    for (int n = 0; n < 4; ++n) {
      int c = tn * 128 + wc * 64 + n * 16 + l15;
#pragma unroll
      for (int j = 0; j < 4; ++j) {
        float v = acc[m][n][j] + bo[c] + res[(size_t)(r + j) * D_ + c];
        out[(size_t)(r + j) * D_ + c] = v;
        x2bf[(size_t)(r + j) * D_ + c] = f2bf(v);
      }
    }
  }
}

// ------- MFMA flash attention: 128 q x 128 k tiles, 8 waves, defer-max ------
__global__ __launch_bounds__(512) void attn_mfma_kernel(
    const uint16_t* __restrict__ Qbf, const uint16_t* __restrict__ Kbf,
    const uint16_t* __restrict__ VT, uint16_t* __restrict__ obf) {
  __shared__ __align__(16) uint16_t Ks[2][8192];   // [128 key][64 d] swz
  __shared__ __align__(16) uint16_t Vt[2][8192];   // [64 d][128 k] swz
  __shared__ __align__(16) uint16_t Plds[16384];   // 8 waves x [16 q][128 k]
  int bid = blockIdx.x;
  int swz = (bid & 7) * 32 + (bid >> 3);   // XCD-contiguous (b,h) groups
  int qt = swz & 15, h = (swz >> 4) & 7, b = swz >> 7;
  int t = threadIdx.x, w = t >> 6, l = t & 63;
  int l15 = l & 15, g = l >> 4;
  int qbase = b * S_ + qt * 128;
  bf16x8 qb_[2];
  {
    const uint16_t* qp = Qbf + (size_t)(qbase + w * 16 + l15) * D_ + h * HD_;
#pragma unroll
    for (int ks = 0; ks < 2; ++ks)
      qb_[ks] = *(const bf16x8*)(qp + ks * 32 + g * 8);
  }
  const uint16_t* Kbase = Kbf + (size_t)(b * S_) * D_ + h * HD_;
  const uint16_t* Vbase = VT + (size_t)((b * H_ + h) * HD_) * S_;
  int rk0 = t >> 3, rk1 = 64 + (t >> 3), pk = t & 7;
  int rv0 = t >> 4, rv1 = 32 + (t >> 4), pv = t & 15;
  int ck0 = (pk ^ (rk0 & 7)) << 4, ck1 = (pk ^ (rk1 & 7)) << 4;
  int cv0 = (pv ^ (rv0 & 7)) << 4, cv1 = (pv ^ (rv1 & 7)) << 4;
  int ldst0 = (t & ~63) << 4, ldst1 = (512 + (t & ~63)) << 4;

  auto stage_kv = [&](int kt, int buf) {
    const uint16_t* Kp = Kbase + (size_t)(kt * 128) * D_;
    const uint16_t* Vp = Vbase + kt * 128;
    GLOAD_LDS16((const char*)(Kp + (size_t)rk0 * D_) + ck0, (char*)Ks[buf] + ldst0);
    GLOAD_LDS16((const char*)(Kp + (size_t)rk1 * D_) + ck1, (char*)Ks[buf] + ldst1);
    GLOAD_LDS16((const char*)(Vp + (size_t)rv0 * S_) + cv0, (char*)Vt[buf] + ldst0);
    GLOAD_LDS16((const char*)(Vp + (size_t)rv1 * S_) + cv1, (char*)Vt[buf] + ldst1);
  };

  f32x4 acc_o[4] = {};
  float m_run = -INFINITY, l_run = 0.f;  // state for q = l15 of this wave
  char* Pw = (char*)Plds + w * 4096;
  int swl = (l15 & 7) << 4;

  stage_kv(0, 0);
  int cur = 0;
  for (int kt = 0; kt < S_ / 128; ++kt) {
    if (kt + 1 < S_ / 128) {
      stage_kv(kt + 1, cur ^ 1);
      VMCNT(4);
    } else {
      VMCNT(0);
    }
    BARRIER; MEMBAR;
    const char* KsC = (const char*)Ks[cur];
    const char* VtC = (const char*)Vt[cur];
    f32x4 accs[8] = {};
#pragma unroll
    for (int ks = 0; ks < 2; ++ks) {
#pragma unroll
      for (int m = 0; m < 8; ++m) {
        int row = m * 16 + l15;
        bf16x8 kf = *(const bf16x8*)(KsC +
                        (row * 128 + ((ks * 64 + g * 16) ^ ((row & 7) << 4))));
        PRIO1;
        accs[m] = __builtin_amdgcn_mfma_f32_16x16x32_bf16(kf, qb_[ks], accs[m], 0, 0, 0);
        PRIO0;
      }
    }
    float mx = accs[0][0];
#pragma unroll
    for (int m = 0; m < 8; ++m)
#pragma unroll
      for (int j = 0; j < 4; ++j) mx = fmaxf(mx, accs[m][j]);
    mx = fmaxf(mx, __shfl_xor(mx, 16));
    mx = fmaxf(mx, __shfl_xor(mx, 32));
    if (!__all(mx <= m_run + 8.f)) {
      float mnew = fmaxf(m_run, mx);
      float corr = exp2f(m_run - mnew);
      m_run = mnew;
      l_run *= corr;
      float cj[4];
#pragma unroll
      for (int j = 0; j < 4; ++j) cj[j] = __shfl(corr, g * 4 + j);
#pragma unroll
      for (int n = 0; n < 4; ++n)
#pragma unroll
        for (int j = 0; j < 4; ++j) acc_o[n][j] *= cj[j];
    }
    float sum = 0.f;
#pragma unroll
    for (int m = 0; m < 8; ++m) {
      float p0 = exp2f(accs[m][0] - m_run);
      float p1 = exp2f(accs[m][1] - m_run);
      float p2 = exp2f(accs[m][2] - m_run);
      float p3 = exp2f(accs[m][3] - m_run);
      sum += (p0 + p1) + (p2 + p3);
      uint2 pk2;
      pk2.x = (uint32_t)f2bf(p0) | ((uint32_t)f2bf(p1) << 16);
      pk2.y = (uint32_t)f2bf(p2) | ((uint32_t)f2bf(p3) << 16);
      *(uint2*)(Pw + (l15 * 256 + ((m * 32 + g * 8) ^ swl))) = pk2;
    }
    sum += __shfl_xor(sum, 16);
    sum += __shfl_xor(sum, 32);
    l_run += sum;
#pragma unroll
    for (int s = 0; s < 4; ++s) {
      bf16x8 pa = *(const bf16x8*)(Pw + (l15 * 256 + ((s * 64 + g * 16) ^ swl)));
#pragma unroll
      for (int n = 0; n < 4; ++n) {
        int d = n * 16 + l15;
        bf16x8 vb = *(const bf16x8*)(VtC +
                        (d * 256 + ((s * 64 + g * 16) ^ ((d & 7) << 4))));
        PRIO1;
        acc_o[n] = __builtin_amdgcn_mfma_f32_16x16x32_bf16(pa, vb, acc_o[n], 0, 0, 0);
        PRIO0;
      }
    }
    MEMBAR; BARRIER;
    cur ^= 1;
  }
#pragma unroll
  for (int j = 0; j < 4; ++j) {
    float lr = __shfl(l_run, g * 4 + j);
    float inv = 1.f / lr;
    uint16_t* op = obf + (size_t)(qbase + w * 16 + g * 4 + j) * D_ + h * HD_;
#pragma unroll
    for (int n = 0; n < 4; ++n)
      op[n * 16 + l15] = f2bf(acc_o[n][j] * inv);
  }
}

// ---------------- MoE FF1 (gathered A), swizzled dbuf, experts via grid.z ---
__global__ __launch_bounds__(256) void ff1_mfma_kernel(
    const uint16_t* __restrict__ X, const uint16_t* __restrict__ w1T,
    const float* __restrict__ b1, const int* __restrict__ list,
    const int* __restrict__ poff, uint16_t* __restrict__ hid) {
  __shared__ __align__(16) uint16_t As[2][8192], Bs[2][8192];
  int tm = blockIdx.x, tn = blockIdx.y, e = blockIdx.z;
  int slot0 = tm * 128;
  if (slot0 >= poff[G_]) return;
  int g_ = 0;
#pragma unroll
  for (int gg = 1; gg < G_; ++gg) g_ += (slot0 >= poff[gg]);
  int t = threadIdx.x;
  int w = t >> 6, l = t & 63, l15 = l & 15, g = l >> 4;
  int wr = w >> 1, wc = w & 1;
  int r8 = t >> 3, clog = (t & 7) ^ (r8 & 7);
  int ubase = (t & ~63) * 8;
  int tok[4];
#pragma unroll
  for (int pi = 0; pi < 4; ++pi) tok[pi] = list[slot0 + pi * 32 + r8];
  const uint16_t* Bb = w1T + ((size_t)(g_ * E_ + e) * FF_ + tn * 128) * D_;
  f32x4 acc[4][4] = {};
  auto stage = [&](int k0, int buf) {
#pragma unroll
    for (int pi = 0; pi < 4; ++pi) {
      GLOAD_LDS16(X + (size_t)tok[pi] * D_ + k0 + clog * 8, As[buf] + pi * 2048 + ubase);
      GLOAD_LDS16(Bb + (size_t)(pi * 32 + r8) * D_ + k0 + clog * 8,
                  Bs[buf] + pi * 2048 + ubase);
    }
  };
  stage(0, 0);
  int cur = 0;
  for (int ki = 0; ki < 8; ++ki) {
    if (ki + 1 < 8) {
      stage((ki + 1) * 64, cur ^ 1);
      VMCNT(8);
    } else {
      VMCNT(0);
    }
    BARRIER; MEMBAR;
    kstep_swz((const char*)As[cur], (const char*)Bs[cur], wr, wc, l15, g, acc);
    MEMBAR; BARRIER;
    cur ^= 1;
  }
  const float* bias = b1 + (size_t)(g_ * E_ + e) * FF_;
  uint16_t* hidE = hid + (size_t)e * PADCAP_ * FF_;
#pragma unroll
  for (int m = 0; m < 4; ++m) {
    int r = slot0 + wr * 64 + m * 16 + g * 4;
#pragma unroll
    for (int n = 0; n < 4; ++n) {
      int c = tn * 128 + wc * 64 + n * 16 + l15;
#pragma unroll
      for (int j = 0; j < 4; ++j)
        hidE[(size_t)(r + j) * FF_ + c] = f2bf(gelu_f(acc[m][n][j] + bias[c]));
    }
  }
}

// ------- MoE FF2: 64x128 tile, 3-buffer / 2-deep prefetch (HBM-latency) -----
// hid (36 MB) overflows L2 -> ~900cy load latency; keep TWO K-tiles in
// flight: issue k+2, wait vmcnt(12) (= 2 tiles x 6 loads newer than tile k).
__global__ __launch_bounds__(256) void ff2_mfma_kernel(
    const uint16_t* __restrict__ hid, const uint16_t* __restrict__ w2T,
    const float* __restrict__ b2, const int* __restrict__ list,
    const int* __restrict__ poff, float* __restrict__ out) {
  __shared__ __align__(16) uint16_t As[3][4096];   // 64 x 64k swizzled
  __shared__ __align__(16) uint16_t Bs[3][8192];   // 128 x 64k swizzled
  int tm = blockIdx.x, tn = blockIdx.y, e = blockIdx.z;
  int slot0 = tm * 64;
  if (slot0 >= poff[G_]) return;
  int g_ = 0;
#pragma unroll
  for (int gg = 1; gg < G_; ++gg) g_ += (slot0 >= poff[gg]);
  int t = threadIdx.x;
  int w = t >> 6, l = t & 63, l15 = l & 15, g = l >> 4;
  int wr = w >> 1, wc = w & 1;
  int r8 = t >> 3, clog = (t & 7) ^ (r8 & 7);
  int ubase = (t & ~63) * 8;
  const uint16_t* Ab = hid + ((size_t)e * PADCAP_ + slot0) * FF_;
  const uint16_t* Bb = w2T + (size_t)(g_ * E_ + e) * D_ * FF_ + (size_t)(tn * 128) * FF_;
  f32x4 acc[2][4] = {};
  auto stage = [&](int k0, int buf) {
#pragma unroll
    for (int pi = 0; pi < 2; ++pi)
      GLOAD_LDS16(Ab + (size_t)(pi * 32 + r8) * FF_ + k0 + clog * 8,
                  As[buf] + pi * 2048 + ubase);
#pragma unroll
    for (int pi = 0; pi < 4; ++pi)
      GLOAD_LDS16(Bb + (size_t)(pi * 32 + r8) * FF_ + k0 + clog * 8,
                  Bs[buf] + pi * 2048 + ubase);
  };
  stage(0, 0);
  stage(64, 1);
  for (int ki = 0; ki < 32; ++ki) {
    int cur = ki % 3;
    if (ki + 2 < 32) {
      stage((ki + 2) * 64, (ki + 2) % 3);
      VMCNT(12);        // 2 newer tiles (6 loads each) stay in flight
    } else if (ki + 1 < 32) {
      VMCNT(6);
    } else {
      VMCNT(0);
    }
    BARRIER; MEMBAR;
    const char* Ac = (const char*)As[cur];
    const char* Bc = (const char*)Bs[cur];
#pragma unroll
    for (int ks = 0; ks < 2; ++ks) {
      int co = (((ks << 2) | g) ^ (l15 & 7)) << 4;
      bf16x8 a[2], b[4];
#pragma unroll
      for (int m = 0; m < 2; ++m)
        a[m] = *(const bf16x8*)(Ac + (wr * 32 + m * 16 + l15) * 128 + co);
#pragma unroll
      for (int n = 0; n < 4; ++n)
        b[n] = *(const bf16x8*)(Bc + (wc * 64 + n * 16 + l15) * 128 + co);
      PRIO1;
#pragma unroll
      for (int m = 0; m < 2; ++m)
#pragma unroll
        for (int n = 0; n < 4; ++n)
          acc[m][n] = __builtin_amdgcn_mfma_f32_16x16x32_bf16(a[m], b[n], acc[m][n], 0, 0, 0);
      PRIO0;
    }
    MEMBAR; BARRIER;
  }
  const float* be = b2 + (size_t)(g_ * E_ + e) * D_;
#pragma unroll
  for (int m = 0; m < 2; ++m) {
    int rbase = slot0 + wr * 32 + m * 16 + g * 4;
#pragma unroll
    for (int j = 0; j < 4; ++j) {
      int tok = list[rbase + j];
      if (tok >= N_) continue;
#pragma unroll
      for (int n = 0; n < 4; ++n) {
        int c = tn * 128 + wc * 64 + n * 16 + l15;
        atomicAdd(&out[(size_t)tok * D_ + c], 0.5f * (acc[m][n][j] + be[c]));
      }
    }
  }
}

}  // namespace

extern "C" void kernel_launch(void* const* d_in, const int* in_sizes, int n_in,
                              void* d_out, int out_size, void* d_ws, size_t ws_size,
                              hipStream_t stream) {
  const float* x = (const float*)d_in[0];
  const int* gid = (const int*)d_in[1];
  const float* ln1s = (const float*)d_in[2];
  const float* ln1b = (const float*)d_in[3];
  const float* ck = (const float*)d_in[4];
  const float* cb = (const float*)d_in[5];
  const float* ln2s = (const float*)d_in[6];
  const float* ln2b = (const float*)d_in[7];
  const float* wq = (const float*)d_in[8];
  const float* bq = (const float*)d_in[9];
  const float* wk = (const float*)d_in[10];
  const float* bk = (const float*)d_in[11];
  const float* wv = (const float*)d_in[12];
  const float* bv = (const float*)d_in[13];
  const float* wo = (const float*)d_in[14];
  const float* bo = (const float*)d_in[15];
  const float* w1 = (const float*)d_in[16];
  const float* b1 = (const float*)d_in[17];
  const float* w2 = (const float*)d_in[18];
  const float* b2 = (const float*)d_in[19];
  float* out = (float*)d_out;

  char* ws = (char*)d_ws;
  // Region A (38 MiB), time-multiplexed:
  //  conv:  P[8] bf16 partials (32 MiB) | ln2bf at +32MiB (4 MiB)
  //  attn:  Qbf(0) | Kbf(+4) | VT(+8) | obf(+12)
  //  moe:   hidbf (2 x 4608 x 2048 bf16 = 36 MiB)
  char* A = ws;
  uint16_t* P = (uint16_t*)A;
  uint16_t* ln2bf = (uint16_t*)(A + (32ull << 20));
  uint16_t* Qbf = (uint16_t*)A;
  uint16_t* Kbf = (uint16_t*)(A + (4ull << 20));
  uint16_t* VT = (uint16_t*)(A + (8ull << 20));
  uint16_t* obf = (uint16_t*)(A + (12ull << 20));
  uint16_t* hidbf = (uint16_t*)A;

  float* x1 = (float*)(ws + (38ull << 20));
  uint16_t* Hpad = (uint16_t*)(ws + (46ull << 20));
  uint16_t* ckT = (uint16_t*)(ws + (51ull << 20));
  uint16_t* wqkvT = (uint16_t*)(ws + (67ull << 20));
  uint16_t* woT = (uint16_t*)(ws + (69ull << 20));
  uint16_t* w1T = (uint16_t*)(ws + (70ull << 20));
  uint16_t* w2T = (uint16_t*)(ws + (86ull << 20));
  uint16_t* x2bf = (uint16_t*)(ws + (102ull << 20));
  int* list = (int*)(ws + (107ull << 20));
  int* poff = list + PADCAP_;

  prep_kernel<<<29502, 256, 0, stream>>>(ck, wq, wk, wv, wo, w1, w2,
                                         ckT, wqkvT, woT, w1T, w2T, Hpad, x2bf,
                                         x, ln1s, ln1b, gid, list, poff);

  // conv sublayer (+ fused LN2)
  conv_mfma_kernel<<<256, 512, 0, stream>>>(Hpad, ckT, P);
  epi_ln_kernel<<<1024, 256, 0, stream>>>(P, cb, x, ln2s, ln2b, x1, ln2bf);

  // attention sublayer
  gemm_qkv_kernel<<<dim3(32, 12), 256, 0, stream>>>(ln2bf, wqkvT, bq, bk, bv, Qbf, Kbf, VT);
  attn_mfma_kernel<<<256, 512, 0, stream>>>(Qbf, Kbf, VT, obf);
  gemm_wo_kernel<<<dim3(32, 4), 256, 0, stream>>>(obf, woT, bo, x1, out, x2bf);

  // MoE sublayer
  ff1_mfma_kernel<<<dim3(36, 16, 2), 256, 0, stream>>>(x2bf, w1T, b1, list, poff, hidbf);
  ff2_mfma_kernel<<<dim3(72, 4, 2), 256, 0, stream>>>(hidbf, w2T, b2, list, poff, out);
}

// Round 18
// 287.179 us; speedup vs baseline: 1.1218x; 1.1218x over previous
//
#include <hip/hip_runtime.h>
#include <hip/hip_bf16.h>
#include <math.h>
#include <stdint.h>

namespace {

constexpr int B_ = 2, S_ = 2048, D_ = 512, H_ = 8, HD_ = 64, K_ = 31,
              FF_ = 2048, G_ = 4, E_ = 2;
constexpr int N_ = B_ * S_;
constexpr int SP_ = S_ + 30;   // padded rows per batch (15 zeros each side)
constexpr float EPS_ = 1e-6f;
constexpr int PADCAP_ = 4608;  // 4096 + 4*127 rounded up to 128-tiles

typedef __bf16 bf16x8 __attribute__((ext_vector_type(8)));
typedef unsigned short u16x8 __attribute__((ext_vector_type(8)));
typedef unsigned short u16x4 __attribute__((ext_vector_type(4)));
typedef float f32x4 __attribute__((ext_vector_type(4)));

__device__ __forceinline__ uint16_t f2bf(float f) {
  union { float f; uint32_t u; } v; v.f = f;
  uint32_t r = v.u + 0x7FFFu + ((v.u >> 16) & 1u);
  return (uint16_t)(r >> 16);
}
__device__ __forceinline__ float bf2f(uint16_t u) {
  union { uint32_t u; float f; } v; v.u = (uint32_t)u << 16;
  return v.f;
}

__device__ __forceinline__ float gelu_f(float x) {
  const float c = 0.7978845608028654f;  // sqrt(2/pi)
  return 0.5f * x * (1.0f + tanhf(c * (x + 0.044715f * x * x * x)));
}

#define GLOAD_LDS16(gsrc, ldst)                                              \
  __builtin_amdgcn_global_load_lds(                                          \
      (const __attribute__((address_space(1))) void*)(gsrc),                 \
      (__attribute__((address_space(3))) void*)(ldst), 16, 0, 0)

#define VMCNT(n) asm volatile("s_waitcnt vmcnt(" #n ")" ::: "memory")
#define MEMBAR asm volatile("" ::: "memory")
#define BARRIER __builtin_amdgcn_s_barrier()
#define PRIO1 __builtin_amdgcn_s_setprio(1)
#define PRIO0 __builtin_amdgcn_s_setprio(0)

// ---- swizzled-tile K-step: tiles are [rows][64 k] bf16, 128B rows,
// chunk c (16B) of row r lives at byte r*128 + (c ^ (r&7))*16.
__device__ __forceinline__ void kstep_swz(const char* As, const char* Bs,
                                          int wr, int wc, int l15, int g,
                                          f32x4 acc[4][4]) {
#pragma unroll
  for (int ks = 0; ks < 2; ++ks) {
    int co = (((ks << 2) | g) ^ (l15 & 7)) << 4;
    bf16x8 a[4], b[4];
#pragma unroll
    for (int m = 0; m < 4; ++m)
      a[m] = *(const bf16x8*)(As + (wr * 64 + m * 16 + l15) * 128 + co);
#pragma unroll
    for (int n = 0; n < 4; ++n)
      b[n] = *(const bf16x8*)(Bs + (wc * 64 + n * 16 + l15) * 128 + co);
    PRIO1;
#pragma unroll
    for (int m = 0; m < 4; ++m)
#pragma unroll
      for (int n = 0; n < 4; ++n)
        acc[m][n] = __builtin_amdgcn_mfma_f32_16x16x32_bf16(a[m], b[n], acc[m][n], 0, 0, 0);
    PRIO0;
  }
}

// Double-buffered BK=64 K-loop, swizzled tiles, counted vmcnt(8).
template <int NK>
__device__ __forceinline__ void gemm_k_dbuf64(const uint16_t* Ab, int lda,
                                              const uint16_t* Bb, int ldb,
                                              int t, int wr, int wc, int l15, int g,
                                              uint16_t (*As)[8192], uint16_t (*Bs)[8192],
                                              f32x4 acc[4][4]) {
  int r8 = t >> 3, clog = (t & 7) ^ (r8 & 7);
  int ubase = (t & ~63) * 8;
  auto stage = [&](int k0, int buf) {
#pragma unroll
    for (int pi = 0; pi < 4; ++pi) {
      int row = pi * 32 + r8;
      GLOAD_LDS16(Ab + (size_t)row * lda + k0 + clog * 8, As[buf] + pi * 2048 + ubase);
      GLOAD_LDS16(Bb + (size_t)row * ldb + k0 + clog * 8, Bs[buf] + pi * 2048 + ubase);
    }
  };
  stage(0, 0);
  int cur = 0;
  for (int ki = 0; ki < NK; ++ki) {
    if (ki + 1 < NK) {
      stage((ki + 1) * 64, cur ^ 1);
      VMCNT(8);
    } else {
      VMCNT(0);
    }
    BARRIER; MEMBAR;
    kstep_swz((const char*)As[cur], (const char*)Bs[cur], wr, wc, l15, g, acc);
    MEMBAR; BARRIER;
    cur ^= 1;
  }
}

// -------- fused prep: weight transposes + zero pad + bucket + LN1 -----------
__global__ __launch_bounds__(256) void prep_kernel(
    const float* __restrict__ ck, const float* __restrict__ wq,
    const float* __restrict__ wk, const float* __restrict__ wv,
    const float* __restrict__ wo, const float* __restrict__ w1,
    const float* __restrict__ w2, uint16_t* __restrict__ ckT,
    uint16_t* __restrict__ wqkvT, uint16_t* __restrict__ woT,
    uint16_t* __restrict__ w1T, uint16_t* __restrict__ w2T,
    uint16_t* __restrict__ Hpad, uint16_t* __restrict__ x2bf,
    const float* __restrict__ x, const float* __restrict__ ln1s,
    const float* __restrict__ ln1b, const int* __restrict__ gid,
    int* __restrict__ list, int* __restrict__ poff) {
  int bi = blockIdx.x, t = threadIdx.x;
  if (bi >= 25406) {  // ---- LN1 rows -> padded Hpad (bf16) ----
    int row = bi - 25406;
    const float* xr = x + (size_t)row * D_;
    float v0 = xr[t], v1 = xr[t + 256];
    float s = v0 + v1, sq = v0 * v0 + v1 * v1;
    for (int o = 32; o > 0; o >>= 1) {
      s += __shfl_down(s, o);
      sq += __shfl_down(sq, o);
    }
    __shared__ float sm[8];
    __shared__ float mr[2];
    int lane = t & 63, wid = t >> 6;
    if (lane == 0) { sm[wid] = s; sm[wid + 4] = sq; }
    __syncthreads();
    if (t == 0) {
      float ts = sm[0] + sm[1] + sm[2] + sm[3];
      float tq = sm[4] + sm[5] + sm[6] + sm[7];
      float m = ts / D_;
      mr[0] = m;
      mr[1] = rsqrtf(tq / D_ - m * m + EPS_);
    }
    __syncthreads();
    float m = mr[0], rs = mr[1];
    size_t drow = (size_t)(row >> 11) * SP_ + 15 + (row & 2047);
    uint16_t* orow = Hpad + drow * D_;
    orow[t] = f2bf((v0 - m) * rs * ln1s[t] + ln1b[t]);
    orow[t + 256] = f2bf((v1 - m) * rs * ln1s[t + 256] + ln1b[t + 256]);
    return;
  }
  if (bi == 25405) {  // ---- bucket (single block), groups padded to 128 ----
    __shared__ int cnt[G_], cur[G_];
    if (t < G_) cnt[t] = 0;
    __syncthreads();
    for (int i = t; i < N_; i += 256) atomicAdd(&cnt[gid[i]], 1);
    __syncthreads();
    if (t == 0) {
      int off = 0;
      for (int g = 0; g < G_; ++g) {
        poff[g] = off;
        cur[g] = off;
        off += (cnt[g] + 127) & ~127;
      }
      poff[G_] = off;
    }
    __syncthreads();
    for (int i = t; i < PADCAP_; i += 256) list[i] = N_;
    __syncthreads();
    for (int i = t; i < N_; i += 256) {
      int p = atomicAdd(&cur[gid[i]], 1);
      list[p] = i;
    }
    return;
  }
  if (bi >= 25344) {  // ---- zero-pad blocks ----
    int j4 = bi - 25344;
    uint16_t* dst;
    if (j4 < 60) {
      int b = j4 / 30, j = j4 % 30;
      int row = b * SP_ + (j < 15 ? j : 2048 + j);
      dst = Hpad + (size_t)row * D_;
    } else {
      dst = x2bf + (size_t)N_ * D_;
    }
    dst[t] = 0;
    dst[t + 256] = 0;
    return;
  }
  const float* src;
  uint16_t* dst;
  int R, C, r0, c0;
  if (bi < 7936) {
    int z = bi >> 8, tile = bi & 255;
    R = 512; C = 512;
    c0 = (tile & 15) * 32; r0 = (tile >> 4) * 32;
    src = ck + (size_t)z * 262144; dst = ckT + (size_t)z * 262144;
  } else if (bi < 8960) {
    int idx = bi - 7936, mat = idx >> 8, tile = idx & 255;
    R = 512; C = 512;
    c0 = (tile & 15) * 32; r0 = (tile >> 4) * 32;
    src = mat == 0 ? wq : (mat == 1 ? wk : (mat == 2 ? wv : wo));
    dst = mat == 3 ? woT : wqkvT + (size_t)mat * 262144;
  } else if (bi < 17152) {
    int idx = bi - 8960, z = idx >> 10, tile = idx & 1023;
    R = 512; C = 2048;
    c0 = (tile & 63) * 32; r0 = (tile >> 6) * 32;
    src = w1 + (size_t)z * 1048576; dst = w1T + (size_t)z * 1048576;
  } else {
    int idx = bi - 17152, z = idx >> 10, tile = idx & 1023;
    R = 2048; C = 512;
    c0 = (tile & 15) * 32; r0 = (tile >> 4) * 32;
    src = w2 + (size_t)z * 1048576; dst = w2T + (size_t)z * 1048576;
  }
  __shared__ float tile[32][33];
  int tc = t & 31, tr = t >> 5;
#pragma unroll
  for (int i = 0; i < 4; ++i) {
    int r = tr + i * 8;
    tile[r][tc] = src[(size_t)(r0 + r) * C + c0 + tc];
  }
  __syncthreads();
#pragma unroll
  for (int i = 0; i < 4; ++i) {
    int rr = tr + i * 8;
    dst[(size_t)(c0 + rr) * R + r0 + tc] = f2bf(tile[tc][rr]);
  }
}

// ---------------- conv: 256x256 block, 8 waves, faithful 4-phase schedule ---
__global__ __launch_bounds__(512) void conv_mfma_kernel(
    const uint16_t* __restrict__ Hpad, const uint16_t* __restrict__ ckT,
    uint16_t* __restrict__ Pout) {
  __shared__ __align__(16) uint16_t As[2][20480];
  __shared__ __align__(16) uint16_t Bs[2][16384];
  int bid = blockIdx.x;
  int ks = bid & 7, tmn = bid >> 3, tm = tmn & 15, tn = tmn >> 4;
  int t = threadIdx.x;
  int w = t >> 6, l = t & 63, l15 = l & 15, g = l >> 4;
  int wr = w >> 2, wc = w & 3;
  int row0 = tm * 256, b = row0 >> 11, s0 = row0 & 2047;
  int kb = ks * 4, ntap = (ks == 7) ? 3 : 4;
  const uint16_t* Abase = Hpad + (size_t)(b * SP_ + s0 + kb) * D_;
  int r8 = t >> 3, clog = (t & 7) ^ (r8 & 7);
  int ubase = (t & ~63) * 8;
  f32x4 acc[8][4] = {};

  auto stageA = [&](int d0, int buf) {
#pragma unroll
    for (int pi = 0; pi < 5; ++pi)
      GLOAD_LDS16(Abase + (size_t)(pi * 64 + r8) * D_ + d0 + clog * 8,
                  As[buf] + pi * 4096 + ubase);
  };
  auto stageB = [&](int k, int d0, int buf) {
    const uint16_t* Bk = ckT + (size_t)k * D_ * D_ + (size_t)(tn * 256) * D_;
#pragma unroll
    for (int pi = 0; pi < 4; ++pi)
      GLOAD_LDS16(Bk + (size_t)(pi * 64 + r8) * D_ + d0 + clog * 8,
                  Bs[buf] + pi * 4096 + ubase);
  };

  stageA(0, 0);
  stageB(kb, 0, 0);
  VMCNT(0);
  BARRIER; MEMBAR;

  int acur = 0, bcur = 0;
  for (int di = 0; di < 8; ++di) {
    int d0 = di * 64;
    for (int i = 0; i < ntap; ++i) {
      const char* Ac = (const char*)As[acur];
      const char* Bc = (const char*)Bs[bcur];
      bf16x8 a[4], bb[4];
      auto rdA = [&](int kkq, int mh) {
        int cA = (((kkq << 2) | g) ^ ((i + l15) & 7)) << 4;
#pragma unroll
        for (int mi = 0; mi < 4; ++mi)
          a[mi] = *(const bf16x8*)(Ac + (i + wr * 128 + (mh * 4 + mi) * 16 + l15) * 128 + cA);
      };
      auto rdB = [&](int kkq) {
        int cB = (((kkq << 2) | g) ^ (l15 & 7)) << 4;
#pragma unroll
        for (int n = 0; n < 4; ++n)
          bb[n] = *(const bf16x8*)(Bc + (wc * 64 + n * 16 + l15) * 128 + cB);
      };
      auto mma = [&](int mh) {
        PRIO1;
#pragma unroll
        for (int mi = 0; mi < 4; ++mi)
#pragma unroll
          for (int n = 0; n < 4; ++n)
            acc[mh * 4 + mi][n] = __builtin_amdgcn_mfma_f32_16x16x32_bf16(
                a[mi], bb[n], acc[mh * 4 + mi][n], 0, 0, 0);
        PRIO0;
      };
      // ---- phase 0: rd (mh0,kk0) pre-barrier, stage issue, barrier, MFMA --
      rdA(0, 0); rdB(0);
      MEMBAR;
      if (i + 1 < ntap) {
        stageB(kb + i + 1, d0, bcur ^ 1);
      } else if (di + 1 < 8) {
        stageA(d0 + 64, acur ^ 1);
        stageB(kb, d0 + 64, bcur ^ 1);
      }
      BARRIER;
      mma(0);
      MEMBAR; BARRIER;
      // ---- phase 1: (mh1,kk0), reuse bb ----
      rdA(0, 1);
      MEMBAR;
      BARRIER;
      mma(1);
      MEMBAR; BARRIER;
      // ---- phase 2: (mh0,kk1) ----
      rdA(1, 0); rdB(1);
      MEMBAR;
      BARRIER;
      mma(0);
      MEMBAR; BARRIER;
      // ---- phase 3: (mh1,kk1) + vmcnt for next tap's buffers ----
      rdA(1, 1);
      MEMBAR;
      VMCNT(0);
      BARRIER;
      mma(1);
      MEMBAR; BARRIER;
      bcur ^= 1;
    }
    acur ^= 1;
  }
  uint16_t* P = Pout + (size_t)ks * N_ * D_;
#pragma unroll
  for (int m = 0; m < 8; ++m) {
    int r = row0 + wr * 128 + m * 16 + g * 4;
#pragma unroll
    for (int n = 0; n < 4; ++n) {
      int c = tn * 256 + wc * 64 + n * 16 + l15;
#pragma unroll
      for (int j = 0; j < 4; ++j)
        P[(size_t)(r + j) * D_ + c] = f2bf(acc[m][n][j]);
    }
  }
}

// -------- conv epilogue + LN2 fused: one wave per token row ------------------
__global__ __launch_bounds__(256) void epi_ln_kernel(
    const uint16_t* __restrict__ P, const float* __restrict__ cb,
    const float* __restrict__ xres, const float* __restrict__ ln2s,
    const float* __restrict__ ln2b, float* __restrict__ x1,
    uint16_t* __restrict__ ln2bf) {
  int t = threadIdx.x;
  int row = blockIdx.x * 4 + (t >> 6);
  int l = t & 63, d0 = l * 8;
  size_t base = (size_t)row * D_ + d0;
  float v[8] = {};
#pragma unroll
  for (int q = 0; q < 8; ++q) {
    u16x8 pv = *(const u16x8*)(P + (size_t)q * N_ * D_ + base);
#pragma unroll
    for (int j = 0; j < 8; ++j) v[j] += bf2f(pv[j]);
  }
  float s = 0.f, sq = 0.f;
#pragma unroll
  for (int j = 0; j < 8; ++j) {
    float xv = xres[base + j];
    float vv = gelu_f(v[j] + cb[d0 + j]) + xv;
    v[j] = vv;
    s += vv;
    sq += vv * vv;
  }
  float4 o0 = {v[0], v[1], v[2], v[3]};
  float4 o1 = {v[4], v[5], v[6], v[7]};
  *(float4*)(x1 + base) = o0;
  *(float4*)(x1 + base + 4) = o1;
  for (int o = 1; o < 64; o <<= 1) {
    s += __shfl_xor(s, o);
    sq += __shfl_xor(sq, o);
  }
  float m = s / D_;
  float rs = rsqrtf(sq / D_ - m * m + EPS_);
  u16x8 ob;
#pragma unroll
  for (int j = 0; j < 8; ++j)
    ob[j] = f2bf((v[j] - m) * rs * ln2s[d0 + j] + ln2b[d0 + j]);
  *(u16x8*)(ln2bf + base) = ob;
}

// ------- fused QKV GEMM -> bf16 Q(scaled log2e/8), K row-major, V^T ---------
__global__ __launch_bounds__(256) void gemm_qkv_kernel(
    const uint16_t* __restrict__ A, const uint16_t* __restrict__ BT,
    const float* __restrict__ bq, const float* __restrict__ bk,
    const float* __restrict__ bv, uint16_t* __restrict__ Qb,
    uint16_t* __restrict__ Kb, uint16_t* __restrict__ VT) {
  __shared__ __align__(16) uint16_t As[2][8192], Bs[2][8192];
  int tm = blockIdx.x, tn = blockIdx.y;
  int t = threadIdx.x;
  int w = t >> 6, l = t & 63, l15 = l & 15, g = l >> 4;
  int wr = w >> 1, wc = w & 1;
  int row0 = tm * 128;
  f32x4 acc[4][4] = {};
  gemm_k_dbuf64<8>(A + (size_t)row0 * D_, D_, BT + (size_t)(tn * 128) * D_, D_,
                   t, wr, wc, l15, g, As, Bs, acc);
  int sel = tn >> 2, col0 = (tn & 3) * 128;
  if (sel < 2) {
    uint16_t* dst = sel == 0 ? Qb : Kb;
    const float* bias = sel == 0 ? bq : bk;
    float scl = sel == 0 ? 0.18033688f : 1.0f;  // (1/8) * log2(e) for exp2 softmax
#pragma unroll
    for (int m = 0; m < 4; ++m) {
      int r = row0 + wr * 64 + m * 16 + g * 4;
#pragma unroll
      for (int n = 0; n < 4; ++n) {
        int c = col0 + wc * 64 + n * 16 + l15;
#pragma unroll
        for (int j = 0; j < 4; ++j)
          dst[(size_t)(r + j) * D_ + c] = f2bf((acc[m][n][j] + bias[c]) * scl);
      }
    }
  } else {
    // V: store transposed [b][h][d][s] for direct attn staging
#pragma unroll
    for (int m = 0; m < 4; ++m) {
      int tb = row0 + wr * 64 + m * 16 + g * 4;
      int b = tb >> 11, s = tb & 2047;
#pragma unroll
      for (int n = 0; n < 4; ++n) {
        int c = col0 + wc * 64 + n * 16 + l15;
        int hh = c >> 6, d = c & 63;
        u16x4 pack;
#pragma unroll
        for (int j = 0; j < 4; ++j) pack[j] = f2bf(acc[m][n][j] + bv[c]);
        *(u16x4*)(VT + ((size_t)((b * H_ + hh) * HD_ + d) * S_ + s)) = pack;
      }
    }
  }
}

// ---------------- WO GEMM + bias + residual -> out (f32) + x2 (bf16) --------
__global__ __launch_bounds__(256) void gemm_wo_kernel(
    const uint16_t* __restrict__ A, const uint16_t* __restrict__ BT,
    const float* __restrict__ bo, const float* __restrict__ res,
    float* __restrict__ out, uint16_t* __restrict__ x2bf) {
  __shared__ __align__(16) uint16_t As[2][8192], Bs[2][8192];
  int tm = blockIdx.x, tn = blockIdx.y;
  int t = threadIdx.x;
  int w = t >> 6, l = t & 63, l15 = l & 15, g = l >> 4;
  int wr = w >> 1, wc = w & 1;
  int row0 = tm * 128;
  f32x4 acc[4][4] = {};
  gemm_k_dbuf64<8>(A + (size_t)row0 * D_, D_, BT + (size_t)(tn * 128) * D_, D_,
                   t, wr, wc, l15, g, As, Bs, acc);
#pragma unroll
  for (int m = 0; m < 4; ++m) {
    int r = row0 + wr * 64 + m * 16 + g * 4;
#pragma unroll
    for (int n = 0; n < 4; ++n) {
      int c = tn * 128 + wc * 64 + n * 16 + l15;
#pragma unroll
      for (int j = 0; j < 4; ++j) {
        float v = acc[m][n][j] + bo[c] + res[(size_t)(r + j) * D_ + c];
        out[(size_t)(r + j) * D_ + c] = v;
        x2bf[(size_t)(r + j) * D_ + c] = f2bf(v);
      }
    }
  }
}

// ------- MFMA flash attention: 128 q x 128 k tiles, 8 waves, defer-max ------
__global__ __launch_bounds__(512) void attn_mfma_kernel(
    const uint16_t* __restrict__ Qbf, const uint16_t* __restrict__ Kbf,
    const uint16_t* __restrict__ VT, uint16_t* __restrict__ obf) {
  __shared__ __align__(16) uint16_t Ks[2][8192];   // [128 key][64 d] swz
  __shared__ __align__(16) uint16_t Vt[2][8192];   // [64 d][128 k] swz
  __shared__ __align__(16) uint16_t Plds[16384];   // 8 waves x [16 q][128 k]
  int bid = blockIdx.x;
  int swz = (bid & 7) * 32 + (bid >> 3);   // XCD-contiguous (b,h) groups
  int qt = swz & 15, h = (swz >> 4) & 7, b = swz >> 7;
  int t = threadIdx.x, w = t >> 6, l = t & 63;
  int l15 = l & 15, g = l >> 4;
  int qbase = b * S_ + qt * 128;
  bf16x8 qb_[2];
  {
    const uint16_t* qp = Qbf + (size_t)(qbase + w * 16 + l15) * D_ + h * HD_;
#pragma unroll
    for (int ks = 0; ks < 2; ++ks)
      qb_[ks] = *(const bf16x8*)(qp + ks * 32 + g * 8);
  }
  const uint16_t* Kbase = Kbf + (size_t)(b * S_) * D_ + h * HD_;
  const uint16_t* Vbase = VT + (size_t)((b * H_ + h) * HD_) * S_;
  int rk0 = t >> 3, rk1 = 64 + (t >> 3), pk = t & 7;
  int rv0 = t >> 4, rv1 = 32 + (t >> 4), pv = t & 15;
  int ck0 = (pk ^ (rk0 & 7)) << 4, ck1 = (pk ^ (rk1 & 7)) << 4;
  int cv0 = (pv ^ (rv0 & 7)) << 4, cv1 = (pv ^ (rv1 & 7)) << 4;
  int ldst0 = (t & ~63) << 4, ldst1 = (512 + (t & ~63)) << 4;

  auto stage_kv = [&](int kt, int buf) {
    const uint16_t* Kp = Kbase + (size_t)(kt * 128) * D_;
    const uint16_t* Vp = Vbase + kt * 128;
    GLOAD_LDS16((const char*)(Kp + (size_t)rk0 * D_) + ck0, (char*)Ks[buf] + ldst0);
    GLOAD_LDS16((const char*)(Kp + (size_t)rk1 * D_) + ck1, (char*)Ks[buf] + ldst1);
    GLOAD_LDS16((const char*)(Vp + (size_t)rv0 * S_) + cv0, (char*)Vt[buf] + ldst0);
    GLOAD_LDS16((const char*)(Vp + (size_t)rv1 * S_) + cv1, (char*)Vt[buf] + ldst1);
  };

  f32x4 acc_o[4] = {};
  float m_run = -INFINITY, l_run = 0.f;  // state for q = l15 of this wave
  char* Pw = (char*)Plds + w * 4096;
  int swl = (l15 & 7) << 4;

  stage_kv(0, 0);
  int cur = 0;
  for (int kt = 0; kt < S_ / 128; ++kt) {
    if (kt + 1 < S_ / 128) {
      stage_kv(kt + 1, cur ^ 1);
      VMCNT(4);
    } else {
      VMCNT(0);
    }
    BARRIER; MEMBAR;
    const char* KsC = (const char*)Ks[cur];
    const char* VtC = (const char*)Vt[cur];
    f32x4 accs[8] = {};
#pragma unroll
    for (int ks = 0; ks < 2; ++ks) {
#pragma unroll
      for (int m = 0; m < 8; ++m) {
        int row = m * 16 + l15;
        bf16x8 kf = *(const bf16x8*)(KsC +
                        (row * 128 + ((ks * 64 + g * 16) ^ ((row & 7) << 4))));
        PRIO1;
        accs[m] = __builtin_amdgcn_mfma_f32_16x16x32_bf16(kf, qb_[ks], accs[m], 0, 0, 0);
        PRIO0;
      }
    }
    float mx = accs[0][0];
#pragma unroll
    for (int m = 0; m < 8; ++m)
#pragma unroll
      for (int j = 0; j < 4; ++j) mx = fmaxf(mx, accs[m][j]);
    mx = fmaxf(mx, __shfl_xor(mx, 16));
    mx = fmaxf(mx, __shfl_xor(mx, 32));
    if (!__all(mx <= m_run + 8.f)) {
      float mnew = fmaxf(m_run, mx);
      float corr = exp2f(m_run - mnew);
      m_run = mnew;
      l_run *= corr;
      float cj[4];
#pragma unroll
      for (int j = 0; j < 4; ++j) cj[j] = __shfl(corr, g * 4 + j);
#pragma unroll
      for (int n = 0; n < 4; ++n)
#pragma unroll
        for (int j = 0; j < 4; ++j) acc_o[n][j] *= cj[j];
    }
    float sum = 0.f;
#pragma unroll
    for (int m = 0; m < 8; ++m) {
      float p0 = exp2f(accs[m][0] - m_run);
      float p1 = exp2f(accs[m][1] - m_run);
      float p2 = exp2f(accs[m][2] - m_run);
      float p3 = exp2f(accs[m][3] - m_run);
      sum += (p0 + p1) + (p2 + p3);
      uint2 pk2;
      pk2.x = (uint32_t)f2bf(p0) | ((uint32_t)f2bf(p1) << 16);
      pk2.y = (uint32_t)f2bf(p2) | ((uint32_t)f2bf(p3) << 16);
      *(uint2*)(Pw + (l15 * 256 + ((m * 32 + g * 8) ^ swl))) = pk2;
    }
    sum += __shfl_xor(sum, 16);
    sum += __shfl_xor(sum, 32);
    l_run += sum;
#pragma unroll
    for (int s = 0; s < 4; ++s) {
      bf16x8 pa = *(const bf16x8*)(Pw + (l15 * 256 + ((s * 64 + g * 16) ^ swl)));
#pragma unroll
      for (int n = 0; n < 4; ++n) {
        int d = n * 16 + l15;
        bf16x8 vb = *(const bf16x8*)(VtC +
                        (d * 256 + ((s * 64 + g * 16) ^ ((d & 7) << 4))));
        PRIO1;
        acc_o[n] = __builtin_amdgcn_mfma_f32_16x16x32_bf16(pa, vb, acc_o[n], 0, 0, 0);
        PRIO0;
      }
    }
    MEMBAR; BARRIER;
    cur ^= 1;
  }
#pragma unroll
  for (int j = 0; j < 4; ++j) {
    float lr = __shfl(l_run, g * 4 + j);
    float inv = 1.f / lr;
    uint16_t* op = obf + (size_t)(qbase + w * 16 + g * 4 + j) * D_ + h * HD_;
#pragma unroll
    for (int n = 0; n < 4; ++n)
      op[n * 16 + l15] = f2bf(acc_o[n][j] * inv);
  }
}

// ---------------- MoE FF1 (gathered A), swizzled dbuf, experts via grid.z ---
__global__ __launch_bounds__(256) void ff1_mfma_kernel(
    const uint16_t* __restrict__ X, const uint16_t* __restrict__ w1T,
    const float* __restrict__ b1, const int* __restrict__ list,
    const int* __restrict__ poff, uint16_t* __restrict__ hid) {
  __shared__ __align__(16) uint16_t As[2][8192], Bs[2][8192];
  int tm = blockIdx.x, tn = blockIdx.y, e = blockIdx.z;
  int slot0 = tm * 128;
  if (slot0 >= poff[G_]) return;
  int g_ = 0;
#pragma unroll
  for (int gg = 1; gg < G_; ++gg) g_ += (slot0 >= poff[gg]);
  int t = threadIdx.x;
  int w = t >> 6, l = t & 63, l15 = l & 15, g = l >> 4;
  int wr = w >> 1, wc = w & 1;
  int r8 = t >> 3, clog = (t & 7) ^ (r8 & 7);
  int ubase = (t & ~63) * 8;
  int tok[4];
#pragma unroll
  for (int pi = 0; pi < 4; ++pi) tok[pi] = list[slot0 + pi * 32 + r8];
  const uint16_t* Bb = w1T + ((size_t)(g_ * E_ + e) * FF_ + tn * 128) * D_;
  f32x4 acc[4][4] = {};
  auto stage = [&](int k0, int buf) {
#pragma unroll
    for (int pi = 0; pi < 4; ++pi) {
      GLOAD_LDS16(X + (size_t)tok[pi] * D_ + k0 + clog * 8, As[buf] + pi * 2048 + ubase);
      GLOAD_LDS16(Bb + (size_t)(pi * 32 + r8) * D_ + k0 + clog * 8,
                  Bs[buf] + pi * 2048 + ubase);
    }
  };
  stage(0, 0);
  int cur = 0;
  for (int ki = 0; ki < 8; ++ki) {
    if (ki + 1 < 8) {
      stage((ki + 1) * 64, cur ^ 1);
      VMCNT(8);
    } else {
      VMCNT(0);
    }
    BARRIER; MEMBAR;
    kstep_swz((const char*)As[cur], (const char*)Bs[cur], wr, wc, l15, g, acc);
    MEMBAR; BARRIER;
    cur ^= 1;
  }
  const float* bias = b1 + (size_t)(g_ * E_ + e) * FF_;
  uint16_t* hidE = hid + (size_t)e * PADCAP_ * FF_;
#pragma unroll
  for (int m = 0; m < 4; ++m) {
    int r = slot0 + wr * 64 + m * 16 + g * 4;
#pragma unroll
    for (int n = 0; n < 4; ++n) {
      int c = tn * 128 + wc * 64 + n * 16 + l15;
#pragma unroll
      for (int j = 0; j < 4; ++j)
        hidE[(size_t)(r + j) * FF_ + c] = f2bf(gelu_f(acc[m][n][j] + bias[c]));
    }
  }
}

// ------- MoE FF2: 64x128 tile, 4 waves (2x2 of 32x64), per-expert, atomic ---
__global__ __launch_bounds__(256) void ff2_mfma_kernel(
    const uint16_t* __restrict__ hid, const uint16_t* __restrict__ w2T,
    const float* __restrict__ b2, const int* __restrict__ list,
    const int* __restrict__ poff, float* __restrict__ out) {
  __shared__ __align__(16) uint16_t As[2][4096];   // 64 x 64k swizzled
  __shared__ __align__(16) uint16_t Bs[2][8192];   // 128 x 64k swizzled
  int tm = blockIdx.x, tn = blockIdx.y, e = blockIdx.z;
  int slot0 = tm * 64;
  if (slot0 >= poff[G_]) return;
  int g_ = 0;
#pragma unroll
  for (int gg = 1; gg < G_; ++gg) g_ += (slot0 >= poff[gg]);
  int t = threadIdx.x;
  int w = t >> 6, l = t & 63, l15 = l & 15, g = l >> 4;
  int wr = w >> 1, wc = w & 1;
  int r8 = t >> 3, clog = (t & 7) ^ (r8 & 7);
  int ubase = (t & ~63) * 8;
  const uint16_t* Ab = hid + ((size_t)e * PADCAP_ + slot0) * FF_;
  const uint16_t* Bb = w2T + (size_t)(g_ * E_ + e) * D_ * FF_ + (size_t)(tn * 128) * FF_;
  f32x4 acc[2][4] = {};
  auto stage = [&](int k0, int buf) {
#pragma unroll
    for (int pi = 0; pi < 2; ++pi)
      GLOAD_LDS16(Ab + (size_t)(pi * 32 + r8) * FF_ + k0 + clog * 8,
                  As[buf] + pi * 2048 + ubase);
#pragma unroll
    for (int pi = 0; pi < 4; ++pi)
      GLOAD_LDS16(Bb + (size_t)(pi * 32 + r8) * FF_ + k0 + clog * 8,
                  Bs[buf] + pi * 2048 + ubase);
  };
  stage(0, 0);
  int cur = 0;
  for (int ki = 0; ki < 32; ++ki) {
    if (ki + 1 < 32) {
      stage((ki + 1) * 64, cur ^ 1);
      VMCNT(6);
    } else {
      VMCNT(0);
    }
    BARRIER; MEMBAR;
    const char* Ac = (const char*)As[cur];
    const char* Bc = (const char*)Bs[cur];
#pragma unroll
    for (int ks = 0; ks < 2; ++ks) {
      int co = (((ks << 2) | g) ^ (l15 & 7)) << 4;
      bf16x8 a[2], b[4];
#pragma unroll
      for (int m = 0; m < 2; ++m)
        a[m] = *(const bf16x8*)(Ac + (wr * 32 + m * 16 + l15) * 128 + co);
#pragma unroll
      for (int n = 0; n < 4; ++n)
        b[n] = *(const bf16x8*)(Bc + (wc * 64 + n * 16 + l15) * 128 + co);
      PRIO1;
#pragma unroll
      for (int m = 0; m < 2; ++m)
#pragma unroll
        for (int n = 0; n < 4; ++n)
          acc[m][n] = __builtin_amdgcn_mfma_f32_16x16x32_bf16(a[m], b[n], acc[m][n], 0, 0, 0);
      PRIO0;
    }
    MEMBAR; BARRIER;
    cur ^= 1;
  }
  const float* be = b2 + (size_t)(g_ * E_ + e) * D_;
#pragma unroll
  for (int m = 0; m < 2; ++m) {
    int rbase = slot0 + wr * 32 + m * 16 + g * 4;
#pragma unroll
    for (int j = 0; j < 4; ++j) {
      int tok = list[rbase + j];
      if (tok >= N_) continue;
#pragma unroll
      for (int n = 0; n < 4; ++n) {
        int c = tn * 128 + wc * 64 + n * 16 + l15;
        atomicAdd(&out[(size_t)tok * D_ + c], 0.5f * (acc[m][n][j] + be[c]));
      }
    }
  }
}

}  // namespace

extern "C" void kernel_launch(void* const* d_in, const int* in_sizes, int n_in,
                              void* d_out, int out_size, void* d_ws, size_t ws_size,
                              hipStream_t stream) {
  const float* x = (const float*)d_in[0];
  const int* gid = (const int*)d_in[1];
  const float* ln1s = (const float*)d_in[2];
  const float* ln1b = (const float*)d_in[3];
  const float* ck = (const float*)d_in[4];
  const float* cb = (const float*)d_in[5];
  const float* ln2s = (const float*)d_in[6];
  const float* ln2b = (const float*)d_in[7];
  const float* wq = (const float*)d_in[8];
  const float* bq = (const float*)d_in[9];
  const float* wk = (const float*)d_in[10];
  const float* bk = (const float*)d_in[11];
  const float* wv = (const float*)d_in[12];
  const float* bv = (const float*)d_in[13];
  const float* wo = (const float*)d_in[14];
  const float* bo = (const float*)d_in[15];
  const float* w1 = (const float*)d_in[16];
  const float* b1 = (const float*)d_in[17];
  const float* w2 = (const float*)d_in[18];
  const float* b2 = (const float*)d_in[19];
  float* out = (float*)d_out;

  char* ws = (char*)d_ws;
  // Region A (38 MiB), time-multiplexed:
  //  conv:  P[8] bf16 partials (32 MiB) | ln2bf at +32MiB (4 MiB)
  //  attn:  Qbf(0) | Kbf(+4) | VT(+8) | obf(+12)
  //  moe:   hidbf (2 x 4608 x 2048 bf16 = 36 MiB)
  char* A = ws;
  uint16_t* P = (uint16_t*)A;
  uint16_t* ln2bf = (uint16_t*)(A + (32ull << 20));
  uint16_t* Qbf = (uint16_t*)A;
  uint16_t* Kbf = (uint16_t*)(A + (4ull << 20));
  uint16_t* VT = (uint16_t*)(A + (8ull << 20));
  uint16_t* obf = (uint16_t*)(A + (12ull << 20));
  uint16_t* hidbf = (uint16_t*)A;

  float* x1 = (float*)(ws + (38ull << 20));
  uint16_t* Hpad = (uint16_t*)(ws + (46ull << 20));
  uint16_t* ckT = (uint16_t*)(ws + (51ull << 20));
  uint16_t* wqkvT = (uint16_t*)(ws + (67ull << 20));
  uint16_t* woT = (uint16_t*)(ws + (69ull << 20));
  uint16_t* w1T = (uint16_t*)(ws + (70ull << 20));
  uint16_t* w2T = (uint16_t*)(ws + (86ull << 20));
  uint16_t* x2bf = (uint16_t*)(ws + (102ull << 20));
  int* list = (int*)(ws + (107ull << 20));
  int* poff = list + PADCAP_;

  prep_kernel<<<29502, 256, 0, stream>>>(ck, wq, wk, wv, wo, w1, w2,
                                         ckT, wqkvT, woT, w1T, w2T, Hpad, x2bf,
                                         x, ln1s, ln1b, gid, list, poff);

  // conv sublayer (+ fused LN2)
  conv_mfma_kernel<<<256, 512, 0, stream>>>(Hpad, ckT, P);
  epi_ln_kernel<<<1024, 256, 0, stream>>>(P, cb, x, ln2s, ln2b, x1, ln2bf);

  // attention sublayer
  gemm_qkv_kernel<<<dim3(32, 12), 256, 0, stream>>>(ln2bf, wqkvT, bq, bk, bv, Qbf, Kbf, VT);
  attn_mfma_kernel<<<256, 512, 0, stream>>>(Qbf, Kbf, VT, obf);
  gemm_wo_kernel<<<dim3(32, 4), 256, 0, stream>>>(obf, woT, bo, x1, out, x2bf);

  // MoE sublayer
  ff1_mfma_kernel<<<dim3(36, 16, 2), 256, 0, stream>>>(x2bf, w1T, b1, list, poff, hidbf);
  ff2_mfma_kernel<<<dim3(72, 4, 2), 256, 0, stream>>>(hidbf, w2T, b2, list, poff, out);
}

// Round 19
// 285.073 us; speedup vs baseline: 1.1301x; 1.0074x over previous
//
#include <hip/hip_runtime.h>
#include <hip/hip_bf16.h>
#include <math.h>
#include <stdint.h>

namespace {

constexpr int B_ = 2, S_ = 2048, D_ = 512, H_ = 8, HD_ = 64, K_ = 31,
              FF_ = 2048, G_ = 4, E_ = 2;
constexpr int N_ = B_ * S_;
constexpr int SP_ = S_ + 30;   // padded rows per batch (15 zeros each side)
constexpr float EPS_ = 1e-6f;
constexpr int PADCAP_ = 4608;  // 4096 + 4*127 rounded up to 128-tiles

typedef __bf16 bf16x8 __attribute__((ext_vector_type(8)));
typedef unsigned short u16x8 __attribute__((ext_vector_type(8)));
typedef unsigned short u16x4 __attribute__((ext_vector_type(4)));
typedef float f32x4 __attribute__((ext_vector_type(4)));

__device__ __forceinline__ uint16_t f2bf(float f) {
  union { float f; uint32_t u; } v; v.f = f;
  uint32_t r = v.u + 0x7FFFu + ((v.u >> 16) & 1u);
  return (uint16_t)(r >> 16);
}
__device__ __forceinline__ float bf2f(uint16_t u) {
  union { uint32_t u; float f; } v; v.u = (uint32_t)u << 16;
  return v.f;
}

__device__ __forceinline__ float gelu_f(float x) {
  const float c = 0.7978845608028654f;  // sqrt(2/pi)
  return 0.5f * x * (1.0f + tanhf(c * (x + 0.044715f * x * x * x)));
}

#define GLOAD_LDS16(gsrc, ldst)                                              \
  __builtin_amdgcn_global_load_lds(                                          \
      (const __attribute__((address_space(1))) void*)(gsrc),                 \
      (__attribute__((address_space(3))) void*)(ldst), 16, 0, 0)

#define VMCNT(n) asm volatile("s_waitcnt vmcnt(" #n ")" ::: "memory")
#define MEMBAR asm volatile("" ::: "memory")
#define BARRIER __builtin_amdgcn_s_barrier()
#define PRIO1 __builtin_amdgcn_s_setprio(1)
#define PRIO0 __builtin_amdgcn_s_setprio(0)

// ---- swizzled-tile K-step: tiles are [rows][64 k] bf16, 128B rows,
// chunk c (16B) of row r lives at byte r*128 + (c ^ (r&7))*16.
__device__ __forceinline__ void kstep_swz(const char* As, const char* Bs,
                                          int wr, int wc, int l15, int g,
                                          f32x4 acc[4][4]) {
#pragma unroll
  for (int ks = 0; ks < 2; ++ks) {
    int co = (((ks << 2) | g) ^ (l15 & 7)) << 4;
    bf16x8 a[4], b[4];
#pragma unroll
    for (int m = 0; m < 4; ++m)
      a[m] = *(const bf16x8*)(As + (wr * 64 + m * 16 + l15) * 128 + co);
#pragma unroll
    for (int n = 0; n < 4; ++n)
      b[n] = *(const bf16x8*)(Bs + (wc * 64 + n * 16 + l15) * 128 + co);
    PRIO1;
#pragma unroll
    for (int m = 0; m < 4; ++m)
#pragma unroll
      for (int n = 0; n < 4; ++n)
        acc[m][n] = __builtin_amdgcn_mfma_f32_16x16x32_bf16(a[m], b[n], acc[m][n], 0, 0, 0);
    PRIO0;
  }
}

// Double-buffered BK=64 K-loop, swizzled tiles, counted vmcnt(8).
template <int NK>
__device__ __forceinline__ void gemm_k_dbuf64(const uint16_t* Ab, int lda,
                                              const uint16_t* Bb, int ldb,
                                              int t, int wr, int wc, int l15, int g,
                                              uint16_t (*As)[8192], uint16_t (*Bs)[8192],
                                              f32x4 acc[4][4]) {
  int r8 = t >> 3, clog = (t & 7) ^ (r8 & 7);
  int ubase = (t & ~63) * 8;
  auto stage = [&](int k0, int buf) {
#pragma unroll
    for (int pi = 0; pi < 4; ++pi) {
      int row = pi * 32 + r8;
      GLOAD_LDS16(Ab + (size_t)row * lda + k0 + clog * 8, As[buf] + pi * 2048 + ubase);
      GLOAD_LDS16(Bb + (size_t)row * ldb + k0 + clog * 8, Bs[buf] + pi * 2048 + ubase);
    }
  };
  stage(0, 0);
  int cur = 0;
  for (int ki = 0; ki < NK; ++ki) {
    if (ki + 1 < NK) {
      stage((ki + 1) * 64, cur ^ 1);
      VMCNT(8);
    } else {
      VMCNT(0);
    }
    BARRIER; MEMBAR;
    kstep_swz((const char*)As[cur], (const char*)Bs[cur], wr, wc, l15, g, acc);
    MEMBAR; BARRIER;
    cur ^= 1;
  }
}

// -------- fused prep: weight transposes + zero pad + bucket + LN1 -----------
__global__ __launch_bounds__(256) void prep_kernel(
    const float* __restrict__ ck, const float* __restrict__ wq,
    const float* __restrict__ wk, const float* __restrict__ wv,
    const float* __restrict__ wo, const float* __restrict__ w1,
    const float* __restrict__ w2, uint16_t* __restrict__ ckT,
    uint16_t* __restrict__ wqkvT, uint16_t* __restrict__ woT,
    uint16_t* __restrict__ w1T, uint16_t* __restrict__ w2T,
    uint16_t* __restrict__ Hpad, uint16_t* __restrict__ x2bf,
    const float* __restrict__ x, const float* __restrict__ ln1s,
    const float* __restrict__ ln1b, const int* __restrict__ gid,
    int* __restrict__ list, int* __restrict__ poff) {
  int bi = blockIdx.x, t = threadIdx.x;
  if (bi >= 25406) {  // ---- LN1 rows -> padded Hpad (bf16) ----
    int row = bi - 25406;
    const float* xr = x + (size_t)row * D_;
    float v0 = xr[t], v1 = xr[t + 256];
    float s = v0 + v1, sq = v0 * v0 + v1 * v1;
    for (int o = 32; o > 0; o >>= 1) {
      s += __shfl_down(s, o);
      sq += __shfl_down(sq, o);
    }
    __shared__ float sm[8];
    __shared__ float mr[2];
    int lane = t & 63, wid = t >> 6;
    if (lane == 0) { sm[wid] = s; sm[wid + 4] = sq; }
    __syncthreads();
    if (t == 0) {
      float ts = sm[0] + sm[1] + sm[2] + sm[3];
      float tq = sm[4] + sm[5] + sm[6] + sm[7];
      float m = ts / D_;
      mr[0] = m;
      mr[1] = rsqrtf(tq / D_ - m * m + EPS_);
    }
    __syncthreads();
    float m = mr[0], rs = mr[1];
    size_t drow = (size_t)(row >> 11) * SP_ + 15 + (row & 2047);
    uint16_t* orow = Hpad + drow * D_;
    orow[t] = f2bf((v0 - m) * rs * ln1s[t] + ln1b[t]);
    orow[t + 256] = f2bf((v1 - m) * rs * ln1s[t + 256] + ln1b[t + 256]);
    return;
  }
  if (bi == 25405) {  // ---- bucket (single block), groups padded to 128 ----
    __shared__ int cnt[G_], cur[G_];
    if (t < G_) cnt[t] = 0;
    __syncthreads();
    for (int i = t; i < N_; i += 256) atomicAdd(&cnt[gid[i]], 1);
    __syncthreads();
    if (t == 0) {
      int off = 0;
      for (int g = 0; g < G_; ++g) {
        poff[g] = off;
        cur[g] = off;
        off += (cnt[g] + 127) & ~127;
      }
      poff[G_] = off;
    }
    __syncthreads();
    for (int i = t; i < PADCAP_; i += 256) list[i] = N_;
    __syncthreads();
    for (int i = t; i < N_; i += 256) {
      int p = atomicAdd(&cur[gid[i]], 1);
      list[p] = i;
    }
    return;
  }
  if (bi >= 25344) {  // ---- zero-pad blocks ----
    int j4 = bi - 25344;
    uint16_t* dst;
    if (j4 < 60) {
      int b = j4 / 30, j = j4 % 30;
      int row = b * SP_ + (j < 15 ? j : 2048 + j);
      dst = Hpad + (size_t)row * D_;
    } else {
      dst = x2bf + (size_t)N_ * D_;
    }
    dst[t] = 0;
    dst[t + 256] = 0;
    return;
  }
  const float* src;
  uint16_t* dst;
  int R, C, r0, c0;
  if (bi < 7936) {
    int z = bi >> 8, tile = bi & 255;
    R = 512; C = 512;
    c0 = (tile & 15) * 32; r0 = (tile >> 4) * 32;
    src = ck + (size_t)z * 262144; dst = ckT + (size_t)z * 262144;
  } else if (bi < 8960) {
    int idx = bi - 7936, mat = idx >> 8, tile = idx & 255;
    R = 512; C = 512;
    c0 = (tile & 15) * 32; r0 = (tile >> 4) * 32;
    src = mat == 0 ? wq : (mat == 1 ? wk : (mat == 2 ? wv : wo));
    dst = mat == 3 ? woT : wqkvT + (size_t)mat * 262144;
  } else if (bi < 17152) {
    int idx = bi - 8960, z = idx >> 10, tile = idx & 1023;
    R = 512; C = 2048;
    c0 = (tile & 63) * 32; r0 = (tile >> 6) * 32;
    src = w1 + (size_t)z * 1048576; dst = w1T + (size_t)z * 1048576;
  } else {
    int idx = bi - 17152, z = idx >> 10, tile = idx & 1023;
    R = 2048; C = 512;
    c0 = (tile & 15) * 32; r0 = (tile >> 4) * 32;
    src = w2 + (size_t)z * 1048576; dst = w2T + (size_t)z * 1048576;
  }
  __shared__ float tile[32][33];
  int tc = t & 31, tr = t >> 5;
#pragma unroll
  for (int i = 0; i < 4; ++i) {
    int r = tr + i * 8;
    tile[r][tc] = src[(size_t)(r0 + r) * C + c0 + tc];
  }
  __syncthreads();
#pragma unroll
  for (int i = 0; i < 4; ++i) {
    int rr = tr + i * 8;
    dst[(size_t)(c0 + rr) * R + r0 + tc] = f2bf(tile[tc][rr]);
  }
}

// ---------------- conv: 256x256 block, 8 waves, faithful 4-phase schedule ---
__global__ __launch_bounds__(512) void conv_mfma_kernel(
    const uint16_t* __restrict__ Hpad, const uint16_t* __restrict__ ckT,
    uint16_t* __restrict__ Pout) {
  __shared__ __align__(16) uint16_t As[2][20480];
  __shared__ __align__(16) uint16_t Bs[2][16384];
  int bid = blockIdx.x;
  int ks = bid & 7, tmn = bid >> 3, tm = tmn & 15, tn = tmn >> 4;
  int t = threadIdx.x;
  int w = t >> 6, l = t & 63, l15 = l & 15, g = l >> 4;
  int wr = w >> 2, wc = w & 3;
  int row0 = tm * 256, b = row0 >> 11, s0 = row0 & 2047;
  int kb = ks * 4, ntap = (ks == 7) ? 3 : 4;
  const uint16_t* Abase = Hpad + (size_t)(b * SP_ + s0 + kb) * D_;
  int r8 = t >> 3, clog = (t & 7) ^ (r8 & 7);
  int ubase = (t & ~63) * 8;
  f32x4 acc[8][4] = {};

  auto stageA = [&](int d0, int buf) {
#pragma unroll
    for (int pi = 0; pi < 5; ++pi)
      GLOAD_LDS16(Abase + (size_t)(pi * 64 + r8) * D_ + d0 + clog * 8,
                  As[buf] + pi * 4096 + ubase);
  };
  auto stageB = [&](int k, int d0, int buf) {
    const uint16_t* Bk = ckT + (size_t)k * D_ * D_ + (size_t)(tn * 256) * D_;
#pragma unroll
    for (int pi = 0; pi < 4; ++pi)
      GLOAD_LDS16(Bk + (size_t)(pi * 64 + r8) * D_ + d0 + clog * 8,
                  Bs[buf] + pi * 4096 + ubase);
  };

  stageA(0, 0);
  stageB(kb, 0, 0);
  VMCNT(0);
  BARRIER; MEMBAR;

  int acur = 0, bcur = 0;
  for (int di = 0; di < 8; ++di) {
    int d0 = di * 64;
    for (int i = 0; i < ntap; ++i) {
      const char* Ac = (const char*)As[acur];
      const char* Bc = (const char*)Bs[bcur];
      bf16x8 a[4], bb[4];
      auto rdA = [&](int kkq, int mh) {
        int cA = (((kkq << 2) | g) ^ ((i + l15) & 7)) << 4;
#pragma unroll
        for (int mi = 0; mi < 4; ++mi)
          a[mi] = *(const bf16x8*)(Ac + (i + wr * 128 + (mh * 4 + mi) * 16 + l15) * 128 + cA);
      };
      auto rdB = [&](int kkq) {
        int cB = (((kkq << 2) | g) ^ (l15 & 7)) << 4;
#pragma unroll
        for (int n = 0; n < 4; ++n)
          bb[n] = *(const bf16x8*)(Bc + (wc * 64 + n * 16 + l15) * 128 + cB);
      };
      auto mma = [&](int mh) {
        PRIO1;
#pragma unroll
        for (int mi = 0; mi < 4; ++mi)
#pragma unroll
          for (int n = 0; n < 4; ++n)
            acc[mh * 4 + mi][n] = __builtin_amdgcn_mfma_f32_16x16x32_bf16(
                a[mi], bb[n], acc[mh * 4 + mi][n], 0, 0, 0);
        PRIO0;
      };
      // ---- phase 0: rd (mh0,kk0) pre-barrier, stage issue, barrier, MFMA --
      rdA(0, 0); rdB(0);
      MEMBAR;
      if (i + 1 < ntap) {
        stageB(kb + i + 1, d0, bcur ^ 1);
      } else if (di + 1 < 8) {
        stageA(d0 + 64, acur ^ 1);
        stageB(kb, d0 + 64, bcur ^ 1);
      }
      BARRIER;
      mma(0);
      MEMBAR; BARRIER;
      // ---- phase 1: (mh1,kk0), reuse bb ----
      rdA(0, 1);
      MEMBAR;
      BARRIER;
      mma(1);
      MEMBAR; BARRIER;
      // ---- phase 2: (mh0,kk1) ----
      rdA(1, 0); rdB(1);
      MEMBAR;
      BARRIER;
      mma(0);
      MEMBAR; BARRIER;
      // ---- phase 3: (mh1,kk1) + vmcnt for next tap's buffers ----
      rdA(1, 1);
      MEMBAR;
      VMCNT(0);
      BARRIER;
      mma(1);
      MEMBAR; BARRIER;
      bcur ^= 1;
    }
    acur ^= 1;
  }
  uint16_t* P = Pout + (size_t)ks * N_ * D_;
#pragma unroll
  for (int m = 0; m < 8; ++m) {
    int r = row0 + wr * 128 + m * 16 + g * 4;
#pragma unroll
    for (int n = 0; n < 4; ++n) {
      int c = tn * 256 + wc * 64 + n * 16 + l15;
#pragma unroll
      for (int j = 0; j < 4; ++j)
        P[(size_t)(r + j) * D_ + c] = f2bf(acc[m][n][j]);
    }
  }
}

// -------- conv epilogue + LN2 fused: one wave per token row ------------------
__global__ __launch_bounds__(256) void epi_ln_kernel(
    const uint16_t* __restrict__ P, const float* __restrict__ cb,
    const float* __restrict__ xres, const float* __restrict__ ln2s,
    const float* __restrict__ ln2b, float* __restrict__ x1,
    uint16_t* __restrict__ ln2bf) {
  int t = threadIdx.x;
  int row = blockIdx.x * 4 + (t >> 6);
  int l = t & 63, d0 = l * 8;
  size_t base = (size_t)row * D_ + d0;
  float v[8] = {};
#pragma unroll
  for (int q = 0; q < 8; ++q) {
    u16x8 pv = *(const u16x8*)(P + (size_t)q * N_ * D_ + base);
#pragma unroll
    for (int j = 0; j < 8; ++j) v[j] += bf2f(pv[j]);
  }
  float s = 0.f, sq = 0.f;
#pragma unroll
  for (int j = 0; j < 8; ++j) {
    float xv = xres[base + j];
    float vv = gelu_f(v[j] + cb[d0 + j]) + xv;
    v[j] = vv;
    s += vv;
    sq += vv * vv;
  }
  float4 o0 = {v[0], v[1], v[2], v[3]};
  float4 o1 = {v[4], v[5], v[6], v[7]};
  *(float4*)(x1 + base) = o0;
  *(float4*)(x1 + base + 4) = o1;
  for (int o = 1; o < 64; o <<= 1) {
    s += __shfl_xor(s, o);
    sq += __shfl_xor(sq, o);
  }
  float m = s / D_;
  float rs = rsqrtf(sq / D_ - m * m + EPS_);
  u16x8 ob;
#pragma unroll
  for (int j = 0; j < 8; ++j)
    ob[j] = f2bf((v[j] - m) * rs * ln2s[d0 + j] + ln2b[d0 + j]);
  *(u16x8*)(ln2bf + base) = ob;
}

// ------- fused QKV GEMM -> bf16 Q(scaled log2e/8), K row-major, V^T ---------
__global__ __launch_bounds__(256) void gemm_qkv_kernel(
    const uint16_t* __restrict__ A, const uint16_t* __restrict__ BT,
    const float* __restrict__ bq, const float* __restrict__ bk,
    const float* __restrict__ bv, uint16_t* __restrict__ Qb,
    uint16_t* __restrict__ Kb, uint16_t* __restrict__ VT) {
  __shared__ __align__(16) uint16_t As[2][8192], Bs[2][8192];
  int tm = blockIdx.x, tn = blockIdx.y;
  int t = threadIdx.x;
  int w = t >> 6, l = t & 63, l15 = l & 15, g = l >> 4;
  int wr = w >> 1, wc = w & 1;
  int row0 = tm * 128;
  f32x4 acc[4][4] = {};
  gemm_k_dbuf64<8>(A + (size_t)row0 * D_, D_, BT + (size_t)(tn * 128) * D_, D_,
                   t, wr, wc, l15, g, As, Bs, acc);
  int sel = tn >> 2, col0 = (tn & 3) * 128;
  if (sel < 2) {
    uint16_t* dst = sel == 0 ? Qb : Kb;
    const float* bias = sel == 0 ? bq : bk;
    float scl = sel == 0 ? 0.18033688f : 1.0f;  // (1/8) * log2(e) for exp2 softmax
#pragma unroll
    for (int m = 0; m < 4; ++m) {
      int r = row0 + wr * 64 + m * 16 + g * 4;
#pragma unroll
      for (int n = 0; n < 4; ++n) {
        int c = col0 + wc * 64 + n * 16 + l15;
#pragma unroll
        for (int j = 0; j < 4; ++j)
          dst[(size_t)(r + j) * D_ + c] = f2bf((acc[m][n][j] + bias[c]) * scl);
      }
    }
  } else {
    // V: store transposed [b][h][d][s] for direct attn staging
#pragma unroll
    for (int m = 0; m < 4; ++m) {
      int tb = row0 + wr * 64 + m * 16 + g * 4;
      int b = tb >> 11, s = tb & 2047;
#pragma unroll
      for (int n = 0; n < 4; ++n) {
        int c = col0 + wc * 64 + n * 16 + l15;
        int hh = c >> 6, d = c & 63;
        u16x4 pack;
#pragma unroll
        for (int j = 0; j < 4; ++j) pack[j] = f2bf(acc[m][n][j] + bv[c]);
        *(u16x4*)(VT + ((size_t)((b * H_ + hh) * HD_ + d) * S_ + s)) = pack;
      }
    }
  }
}

// ---------------- WO GEMM + bias + residual -> out (f32) + x2 (bf16) --------
__global__ __launch_bounds__(256) void gemm_wo_kernel(
    const uint16_t* __restrict__ A, const uint16_t* __restrict__ BT,
    const float* __restrict__ bo, const float* __restrict__ res,
    float* __restrict__ out, uint16_t* __restrict__ x2bf) {
  __shared__ __align__(16) uint16_t As[2][8192], Bs[2][8192];
  int tm = blockIdx.x, tn = blockIdx.y;
  int t = threadIdx.x;
  int w = t >> 6, l = t & 63, l15 = l & 15, g = l >> 4;
  int wr = w >> 1, wc = w & 1;
  int row0 = tm * 128;
  f32x4 acc[4][4] = {};
  gemm_k_dbuf64<8>(A + (size_t)row0 * D_, D_, BT + (size_t)(tn * 128) * D_, D_,
                   t, wr, wc, l15, g, As, Bs, acc);
#pragma unroll
  for (int m = 0; m < 4; ++m) {
    int r = row0 + wr * 64 + m * 16 + g * 4;
#pragma unroll
    for (int n = 0; n < 4; ++n) {
      int c = tn * 128 + wc * 64 + n * 16 + l15;
#pragma unroll
      for (int j = 0; j < 4; ++j) {
        float v = acc[m][n][j] + bo[c] + res[(size_t)(r + j) * D_ + c];
        out[(size_t)(r + j) * D_ + c] = v;
        x2bf[(size_t)(r + j) * D_ + c] = f2bf(v);
      }
    }
  }
}

// ------- MFMA flash attention: 128 q x 128 k tiles, 8 waves, defer-max ------
__global__ __launch_bounds__(512) void attn_mfma_kernel(
    const uint16_t* __restrict__ Qbf, const uint16_t* __restrict__ Kbf,
    const uint16_t* __restrict__ VT, uint16_t* __restrict__ obf) {
  __shared__ __align__(16) uint16_t Ks[2][8192];   // [128 key][64 d] swz
  __shared__ __align__(16) uint16_t Vt[2][8192];   // [64 d][128 k] swz
  __shared__ __align__(16) uint16_t Plds[16384];   // 8 waves x [16 q][128 k]
  int bid = blockIdx.x;
  int swz = (bid & 7) * 32 + (bid >> 3);   // XCD-contiguous (b,h) groups
  int qt = swz & 15, h = (swz >> 4) & 7, b = swz >> 7;
  int t = threadIdx.x, w = t >> 6, l = t & 63;
  int l15 = l & 15, g = l >> 4;
  int qbase = b * S_ + qt * 128;
  bf16x8 qb_[2];
  {
    const uint16_t* qp = Qbf + (size_t)(qbase + w * 16 + l15) * D_ + h * HD_;
#pragma unroll
    for (int ks = 0; ks < 2; ++ks)
      qb_[ks] = *(const bf16x8*)(qp + ks * 32 + g * 8);
  }
  const uint16_t* Kbase = Kbf + (size_t)(b * S_) * D_ + h * HD_;
  const uint16_t* Vbase = VT + (size_t)((b * H_ + h) * HD_) * S_;
  int rk0 = t >> 3, rk1 = 64 + (t >> 3), pk = t & 7;
  int rv0 = t >> 4, rv1 = 32 + (t >> 4), pv = t & 15;
  int ck0 = (pk ^ (rk0 & 7)) << 4, ck1 = (pk ^ (rk1 & 7)) << 4;
  int cv0 = (pv ^ (rv0 & 7)) << 4, cv1 = (pv ^ (rv1 & 7)) << 4;
  int ldst0 = (t & ~63) << 4, ldst1 = (512 + (t & ~63)) << 4;

  auto stage_kv = [&](int kt, int buf) {
    const uint16_t* Kp = Kbase + (size_t)(kt * 128) * D_;
    const uint16_t* Vp = Vbase + kt * 128;
    GLOAD_LDS16((const char*)(Kp + (size_t)rk0 * D_) + ck0, (char*)Ks[buf] + ldst0);
    GLOAD_LDS16((const char*)(Kp + (size_t)rk1 * D_) + ck1, (char*)Ks[buf] + ldst1);
    GLOAD_LDS16((const char*)(Vp + (size_t)rv0 * S_) + cv0, (char*)Vt[buf] + ldst0);
    GLOAD_LDS16((const char*)(Vp + (size_t)rv1 * S_) + cv1, (char*)Vt[buf] + ldst1);
  };

  f32x4 acc_o[4] = {};
  float m_run = -INFINITY, l_run = 0.f;  // state for q = l15 of this wave
  char* Pw = (char*)Plds + w * 4096;
  int swl = (l15 & 7) << 4;

  stage_kv(0, 0);
  int cur = 0;
  for (int kt = 0; kt < S_ / 128; ++kt) {
    if (kt + 1 < S_ / 128) {
      stage_kv(kt + 1, cur ^ 1);
      VMCNT(4);
    } else {
      VMCNT(0);
    }
    BARRIER; MEMBAR;
    const char* KsC = (const char*)Ks[cur];
    const char* VtC = (const char*)Vt[cur];
    f32x4 accs[8] = {};
#pragma unroll
    for (int ks = 0; ks < 2; ++ks) {
#pragma unroll
      for (int m = 0; m < 8; ++m) {
        int row = m * 16 + l15;
        bf16x8 kf = *(const bf16x8*)(KsC +
                        (row * 128 + ((ks * 64 + g * 16) ^ ((row & 7) << 4))));
        PRIO1;
        accs[m] = __builtin_amdgcn_mfma_f32_16x16x32_bf16(kf, qb_[ks], accs[m], 0, 0, 0);
        PRIO0;
      }
    }
    float mx = accs[0][0];
#pragma unroll
    for (int m = 0; m < 8; ++m)
#pragma unroll
      for (int j = 0; j < 4; ++j) mx = fmaxf(mx, accs[m][j]);
    mx = fmaxf(mx, __shfl_xor(mx, 16));
    mx = fmaxf(mx, __shfl_xor(mx, 32));
    if (!__all(mx <= m_run + 8.f)) {
      float mnew = fmaxf(m_run, mx);
      float corr = exp2f(m_run - mnew);
      m_run = mnew;
      l_run *= corr;
      float cj[4];
#pragma unroll
      for (int j = 0; j < 4; ++j) cj[j] = __shfl(corr, g * 4 + j);
#pragma unroll
      for (int n = 0; n < 4; ++n)
#pragma unroll
        for (int j = 0; j < 4; ++j) acc_o[n][j] *= cj[j];
    }
    float sum = 0.f;
#pragma unroll
    for (int m = 0; m < 8; ++m) {
      float p0 = exp2f(accs[m][0] - m_run);
      float p1 = exp2f(accs[m][1] - m_run);
      float p2 = exp2f(accs[m][2] - m_run);
      float p3 = exp2f(accs[m][3] - m_run);
      sum += (p0 + p1) + (p2 + p3);
      uint2 pk2;
      pk2.x = (uint32_t)f2bf(p0) | ((uint32_t)f2bf(p1) << 16);
      pk2.y = (uint32_t)f2bf(p2) | ((uint32_t)f2bf(p3) << 16);
      *(uint2*)(Pw + (l15 * 256 + ((m * 32 + g * 8) ^ swl))) = pk2;
    }
    sum += __shfl_xor(sum, 16);
    sum += __shfl_xor(sum, 32);
    l_run += sum;
#pragma unroll
    for (int s = 0; s < 4; ++s) {
      bf16x8 pa = *(const bf16x8*)(Pw + (l15 * 256 + ((s * 64 + g * 16) ^ swl)));
#pragma unroll
      for (int n = 0; n < 4; ++n) {
        int d = n * 16 + l15;
        bf16x8 vb = *(const bf16x8*)(VtC +
                        (d * 256 + ((s * 64 + g * 16) ^ ((d & 7) << 4))));
        PRIO1;
        acc_o[n] = __builtin_amdgcn_mfma_f32_16x16x32_bf16(pa, vb, acc_o[n], 0, 0, 0);
        PRIO0;
      }
    }
    MEMBAR; BARRIER;
    cur ^= 1;
  }
#pragma unroll
  for (int j = 0; j < 4; ++j) {
    float lr = __shfl(l_run, g * 4 + j);
    float inv = 1.f / lr;
    uint16_t* op = obf + (size_t)(qbase + w * 16 + g * 4 + j) * D_ + h * HD_;
#pragma unroll
    for (int n = 0; n < 4; ++n)
      op[n * 16 + l15] = f2bf(acc_o[n][j] * inv);
  }
}

// ---------------- MoE FF1 (gathered A), swizzled dbuf, experts via grid.z ---
__global__ __launch_bounds__(256) void ff1_mfma_kernel(
    const uint16_t* __restrict__ X, const uint16_t* __restrict__ w1T,
    const float* __restrict__ b1, const int* __restrict__ list,
    const int* __restrict__ poff, uint16_t* __restrict__ hid) {
  __shared__ __align__(16) uint16_t As[2][8192], Bs[2][8192];
  int tm = blockIdx.x, tn = blockIdx.y, e = blockIdx.z;
  int slot0 = tm * 128;
  if (slot0 >= poff[G_]) return;
  int g_ = 0;
#pragma unroll
  for (int gg = 1; gg < G_; ++gg) g_ += (slot0 >= poff[gg]);
  int t = threadIdx.x;
  int w = t >> 6, l = t & 63, l15 = l & 15, g = l >> 4;
  int wr = w >> 1, wc = w & 1;
  int r8 = t >> 3, clog = (t & 7) ^ (r8 & 7);
  int ubase = (t & ~63) * 8;
  int tok[4];
#pragma unroll
  for (int pi = 0; pi < 4; ++pi) tok[pi] = list[slot0 + pi * 32 + r8];
  const uint16_t* Bb = w1T + ((size_t)(g_ * E_ + e) * FF_ + tn * 128) * D_;
  f32x4 acc[4][4] = {};
  auto stage = [&](int k0, int buf) {
#pragma unroll
    for (int pi = 0; pi < 4; ++pi) {
      GLOAD_LDS16(X + (size_t)tok[pi] * D_ + k0 + clog * 8, As[buf] + pi * 2048 + ubase);
      GLOAD_LDS16(Bb + (size_t)(pi * 32 + r8) * D_ + k0 + clog * 8,
                  Bs[buf] + pi * 2048 + ubase);
    }
  };
  stage(0, 0);
  int cur = 0;
  for (int ki = 0; ki < 8; ++ki) {
    if (ki + 1 < 8) {
      stage((ki + 1) * 64, cur ^ 1);
      VMCNT(8);
    } else {
      VMCNT(0);
    }
    BARRIER; MEMBAR;
    kstep_swz((const char*)As[cur], (const char*)Bs[cur], wr, wc, l15, g, acc);
    MEMBAR; BARRIER;
    cur ^= 1;
  }
  const float* bias = b1 + (size_t)(g_ * E_ + e) * FF_;
  uint16_t* hidE = hid + (size_t)e * PADCAP_ * FF_;
#pragma unroll
  for (int m = 0; m < 4; ++m) {
    int r = slot0 + wr * 64 + m * 16 + g * 4;
#pragma unroll
    for (int n = 0; n < 4; ++n) {
      int c = tn * 128 + wc * 64 + n * 16 + l15;
#pragma unroll
      for (int j = 0; j < 4; ++j)
        hidE[(size_t)(r + j) * FF_ + c] = f2bf(gelu_f(acc[m][n][j] + bias[c]));
    }
  }
}

// ------- MoE FF2: 64x128 tile, XCD-grouped A-panel sharers, atomic ----------
// 1-D grid 576; swz=(bid&7)*72+(bid>>3) gives each XCD a contiguous chunk of
// tm in [9x,9x+9) x all 8 (tn,e) -> the 8 blocks sharing an A(hid) panel are
// co-resident on one XCD, so A K-slices are HBM-fetched once and L2-hit 7x.
__global__ __launch_bounds__(256) void ff2_mfma_kernel(
    const uint16_t* __restrict__ hid, const uint16_t* __restrict__ w2T,
    const float* __restrict__ b2, const int* __restrict__ list,
    const int* __restrict__ poff, float* __restrict__ out) {
  __shared__ __align__(16) uint16_t As[2][4096];   // 64 x 64k swizzled
  __shared__ __align__(16) uint16_t Bs[2][8192];   // 128 x 64k swizzled
  int bid = blockIdx.x;
  int swz = (bid & 7) * 72 + (bid >> 3);
  int tm = swz >> 3, tn = swz & 3, e = (swz >> 2) & 1;
  int slot0 = tm * 64;
  if (slot0 >= poff[G_]) return;
  int g_ = 0;
#pragma unroll
  for (int gg = 1; gg < G_; ++gg) g_ += (slot0 >= poff[gg]);
  int t = threadIdx.x;
  int w = t >> 6, l = t & 63, l15 = l & 15, g = l >> 4;
  int wr = w >> 1, wc = w & 1;
  int r8 = t >> 3, clog = (t & 7) ^ (r8 & 7);
  int ubase = (t & ~63) * 8;
  const uint16_t* Ab = hid + ((size_t)e * PADCAP_ + slot0) * FF_;
  const uint16_t* Bb = w2T + (size_t)(g_ * E_ + e) * D_ * FF_ + (size_t)(tn * 128) * FF_;
  f32x4 acc[2][4] = {};
  auto stage = [&](int k0, int buf) {
#pragma unroll
    for (int pi = 0; pi < 2; ++pi)
      GLOAD_LDS16(Ab + (size_t)(pi * 32 + r8) * FF_ + k0 + clog * 8,
                  As[buf] + pi * 2048 + ubase);
#pragma unroll
    for (int pi = 0; pi < 4; ++pi)
      GLOAD_LDS16(Bb + (size_t)(pi * 32 + r8) * FF_ + k0 + clog * 8,
                  Bs[buf] + pi * 2048 + ubase);
  };
  stage(0, 0);
  int cur = 0;
  for (int ki = 0; ki < 32; ++ki) {
    if (ki + 1 < 32) {
      stage((ki + 1) * 64, cur ^ 1);
      VMCNT(6);
    } else {
      VMCNT(0);
    }
    BARRIER; MEMBAR;
    const char* Ac = (const char*)As[cur];
    const char* Bc = (const char*)Bs[cur];
#pragma unroll
    for (int ks = 0; ks < 2; ++ks) {
      int co = (((ks << 2) | g) ^ (l15 & 7)) << 4;
      bf16x8 a[2], b[4];
#pragma unroll
      for (int m = 0; m < 2; ++m)
        a[m] = *(const bf16x8*)(Ac + (wr * 32 + m * 16 + l15) * 128 + co);
#pragma unroll
      for (int n = 0; n < 4; ++n)
        b[n] = *(const bf16x8*)(Bc + (wc * 64 + n * 16 + l15) * 128 + co);
      PRIO1;
#pragma unroll
      for (int m = 0; m < 2; ++m)
#pragma unroll
        for (int n = 0; n < 4; ++n)
          acc[m][n] = __builtin_amdgcn_mfma_f32_16x16x32_bf16(a[m], b[n], acc[m][n], 0, 0, 0);
      PRIO0;
    }
    MEMBAR; BARRIER;
    cur ^= 1;
  }
  const float* be = b2 + (size_t)(g_ * E_ + e) * D_;
#pragma unroll
  for (int m = 0; m < 2; ++m) {
    int rbase = slot0 + wr * 32 + m * 16 + g * 4;
#pragma unroll
    for (int j = 0; j < 4; ++j) {
      int tok = list[rbase + j];
      if (tok >= N_) continue;
#pragma unroll
      for (int n = 0; n < 4; ++n) {
        int c = tn * 128 + wc * 64 + n * 16 + l15;
        atomicAdd(&out[(size_t)tok * D_ + c], 0.5f * (acc[m][n][j] + be[c]));
      }
    }
  }
}

}  // namespace

extern "C" void kernel_launch(void* const* d_in, const int* in_sizes, int n_in,
                              void* d_out, int out_size, void* d_ws, size_t ws_size,
                              hipStream_t stream) {
  const float* x = (const float*)d_in[0];
  const int* gid = (const int*)d_in[1];
  const float* ln1s = (const float*)d_in[2];
  const float* ln1b = (const float*)d_in[3];
  const float* ck = (const float*)d_in[4];
  const float* cb = (const float*)d_in[5];
  const float* ln2s = (const float*)d_in[6];
  const float* ln2b = (const float*)d_in[7];
  const float* wq = (const float*)d_in[8];
  const float* bq = (const float*)d_in[9];
  const float* wk = (const float*)d_in[10];
  const float* bk = (const float*)d_in[11];
  const float* wv = (const float*)d_in[12];
  const float* bv = (const float*)d_in[13];
  const float* wo = (const float*)d_in[14];
  const float* bo = (const float*)d_in[15];
  const float* w1 = (const float*)d_in[16];
  const float* b1 = (const float*)d_in[17];
  const float* w2 = (const float*)d_in[18];
  const float* b2 = (const float*)d_in[19];
  float* out = (float*)d_out;

  char* ws = (char*)d_ws;
  // Region A (38 MiB), time-multiplexed:
  //  conv:  P[8] bf16 partials (32 MiB) | ln2bf at +32MiB (4 MiB)
  //  attn:  Qbf(0) | Kbf(+4) | VT(+8) | obf(+12)
  //  moe:   hidbf (2 x 4608 x 2048 bf16 = 36 MiB)
  char* A = ws;
  uint16_t* P = (uint16_t*)A;
  uint16_t* ln2bf = (uint16_t*)(A + (32ull << 20));
  uint16_t* Qbf = (uint16_t*)A;
  uint16_t* Kbf = (uint16_t*)(A + (4ull << 20));
  uint16_t* VT = (uint16_t*)(A + (8ull << 20));
  uint16_t* obf = (uint16_t*)(A + (12ull << 20));
  uint16_t* hidbf = (uint16_t*)A;

  float* x1 = (float*)(ws + (38ull << 20));
  uint16_t* Hpad = (uint16_t*)(ws + (46ull << 20));
  uint16_t* ckT = (uint16_t*)(ws + (51ull << 20));
  uint16_t* wqkvT = (uint16_t*)(ws + (67ull << 20));
  uint16_t* woT = (uint16_t*)(ws + (69ull << 20));
  uint16_t* w1T = (uint16_t*)(ws + (70ull << 20));
  uint16_t* w2T = (uint16_t*)(ws + (86ull << 20));
  uint16_t* x2bf = (uint16_t*)(ws + (102ull << 20));
  int* list = (int*)(ws + (107ull << 20));
  int* poff = list + PADCAP_;

  prep_kernel<<<29502, 256, 0, stream>>>(ck, wq, wk, wv, wo, w1, w2,
                                         ckT, wqkvT, woT, w1T, w2T, Hpad, x2bf,
                                         x, ln1s, ln1b, gid, list, poff);

  // conv sublayer (+ fused LN2)
  conv_mfma_kernel<<<256, 512, 0, stream>>>(Hpad, ckT, P);
  epi_ln_kernel<<<1024, 256, 0, stream>>>(P, cb, x, ln2s, ln2b, x1, ln2bf);

  // attention sublayer
  gemm_qkv_kernel<<<dim3(32, 12), 256, 0, stream>>>(ln2bf, wqkvT, bq, bk, bv, Qbf, Kbf, VT);
  attn_mfma_kernel<<<256, 512, 0, stream>>>(Qbf, Kbf, VT, obf);
  gemm_wo_kernel<<<dim3(32, 4), 256, 0, stream>>>(obf, woT, bo, x1, out, x2bf);

  // MoE sublayer
  ff1_mfma_kernel<<<dim3(36, 16, 2), 256, 0, stream>>>(x2bf, w1T, b1, list, poff, hidbf);
  ff2_mfma_kernel<<<576, 256, 0, stream>>>(hidbf, w2T, b2, list, poff, out);
}

// Round 20
// 283.932 us; speedup vs baseline: 1.1347x; 1.0040x over previous
//
#include <hip/hip_runtime.h>
#include <hip/hip_bf16.h>
#include <math.h>
#include <stdint.h>

namespace {

constexpr int B_ = 2, S_ = 2048, D_ = 512, H_ = 8, HD_ = 64, K_ = 31,
              FF_ = 2048, G_ = 4, E_ = 2;
constexpr int N_ = B_ * S_;
constexpr int SP_ = S_ + 30;   // padded rows per batch (15 zeros each side)
constexpr float EPS_ = 1e-6f;
constexpr int PADCAP_ = 4608;  // 4096 + 4*127 rounded up to 128-tiles

typedef __bf16 bf16x8 __attribute__((ext_vector_type(8)));
typedef unsigned short u16x8 __attribute__((ext_vector_type(8)));
typedef unsigned short u16x4 __attribute__((ext_vector_type(4)));
typedef float f32x4 __attribute__((ext_vector_type(4)));

__device__ __forceinline__ uint16_t f2bf(float f) {
  union { float f; uint32_t u; } v; v.f = f;
  uint32_t r = v.u + 0x7FFFu + ((v.u >> 16) & 1u);
  return (uint16_t)(r >> 16);
}
__device__ __forceinline__ float bf2f(uint16_t u) {
  union { uint32_t u; float f; } v; v.u = (uint32_t)u << 16;
  return v.f;
}

__device__ __forceinline__ float gelu_f(float x) {
  const float c = 0.7978845608028654f;  // sqrt(2/pi)
  return 0.5f * x * (1.0f + tanhf(c * (x + 0.044715f * x * x * x)));
}

#define GLOAD_LDS16(gsrc, ldst)                                              \
  __builtin_amdgcn_global_load_lds(                                          \
      (const __attribute__((address_space(1))) void*)(gsrc),                 \
      (__attribute__((address_space(3))) void*)(ldst), 16, 0, 0)

#define VMCNT(n) asm volatile("s_waitcnt vmcnt(" #n ")" ::: "memory")
#define MEMBAR asm volatile("" ::: "memory")
#define BARRIER __builtin_amdgcn_s_barrier()
#define PRIO1 __builtin_amdgcn_s_setprio(1)
#define PRIO0 __builtin_amdgcn_s_setprio(0)

// ---- swizzled-tile K-step: tiles are [rows][64 k] bf16, 128B rows,
// chunk c (16B) of row r lives at byte r*128 + (c ^ (r&7))*16.
__device__ __forceinline__ void kstep_swz(const char* As, const char* Bs,
                                          int wr, int wc, int l15, int g,
                                          f32x4 acc[4][4]) {
#pragma unroll
  for (int ks = 0; ks < 2; ++ks) {
    int co = (((ks << 2) | g) ^ (l15 & 7)) << 4;
    bf16x8 a[4], b[4];
#pragma unroll
    for (int m = 0; m < 4; ++m)
      a[m] = *(const bf16x8*)(As + (wr * 64 + m * 16 + l15) * 128 + co);
#pragma unroll
    for (int n = 0; n < 4; ++n)
      b[n] = *(const bf16x8*)(Bs + (wc * 64 + n * 16 + l15) * 128 + co);
    PRIO1;
#pragma unroll
    for (int m = 0; m < 4; ++m)
#pragma unroll
      for (int n = 0; n < 4; ++n)
        acc[m][n] = __builtin_amdgcn_mfma_f32_16x16x32_bf16(a[m], b[n], acc[m][n], 0, 0, 0);
    PRIO0;
  }
}

// Double-buffered BK=64 K-loop, swizzled tiles, counted vmcnt(8).
template <int NK>
__device__ __forceinline__ void gemm_k_dbuf64(const uint16_t* Ab, int lda,
                                              const uint16_t* Bb, int ldb,
                                              int t, int wr, int wc, int l15, int g,
                                              uint16_t (*As)[8192], uint16_t (*Bs)[8192],
                                              f32x4 acc[4][4]) {
  int r8 = t >> 3, clog = (t & 7) ^ (r8 & 7);
  int ubase = (t & ~63) * 8;
  auto stage = [&](int k0, int buf) {
#pragma unroll
    for (int pi = 0; pi < 4; ++pi) {
      int row = pi * 32 + r8;
      GLOAD_LDS16(Ab + (size_t)row * lda + k0 + clog * 8, As[buf] + pi * 2048 + ubase);
      GLOAD_LDS16(Bb + (size_t)row * ldb + k0 + clog * 8, Bs[buf] + pi * 2048 + ubase);
    }
  };
  stage(0, 0);
  int cur = 0;
  for (int ki = 0; ki < NK; ++ki) {
    if (ki + 1 < NK) {
      stage((ki + 1) * 64, cur ^ 1);
      VMCNT(8);
    } else {
      VMCNT(0);
    }
    BARRIER; MEMBAR;
    kstep_swz((const char*)As[cur], (const char*)Bs[cur], wr, wc, l15, g, acc);
    MEMBAR; BARRIER;
    cur ^= 1;
  }
}

// -------- fused prep: weight transposes + zero pad + bucket + LN1 -----------
__global__ __launch_bounds__(256) void prep_kernel(
    const float* __restrict__ ck, const float* __restrict__ wq,
    const float* __restrict__ wk, const float* __restrict__ wv,
    const float* __restrict__ wo, const float* __restrict__ w1,
    const float* __restrict__ w2, uint16_t* __restrict__ ckT,
    uint16_t* __restrict__ wqkvT, uint16_t* __restrict__ woT,
    uint16_t* __restrict__ w1T, uint16_t* __restrict__ w2T,
    uint16_t* __restrict__ Hpad, uint16_t* __restrict__ x2bf,
    const float* __restrict__ x, const float* __restrict__ ln1s,
    const float* __restrict__ ln1b, const int* __restrict__ gid,
    int* __restrict__ list, int* __restrict__ poff) {
  int bi = blockIdx.x, t = threadIdx.x;
  if (bi >= 25406) {  // ---- LN1 rows -> padded Hpad (bf16) ----
    int row = bi - 25406;
    const float* xr = x + (size_t)row * D_;
    float v0 = xr[t], v1 = xr[t + 256];
    float s = v0 + v1, sq = v0 * v0 + v1 * v1;
    for (int o = 32; o > 0; o >>= 1) {
      s += __shfl_down(s, o);
      sq += __shfl_down(sq, o);
    }
    __shared__ float sm[8];
    __shared__ float mr[2];
    int lane = t & 63, wid = t >> 6;
    if (lane == 0) { sm[wid] = s; sm[wid + 4] = sq; }
    __syncthreads();
    if (t == 0) {
      float ts = sm[0] + sm[1] + sm[2] + sm[3];
      float tq = sm[4] + sm[5] + sm[6] + sm[7];
      float m = ts / D_;
      mr[0] = m;
      mr[1] = rsqrtf(tq / D_ - m * m + EPS_);
    }
    __syncthreads();
    float m = mr[0], rs = mr[1];
    size_t drow = (size_t)(row >> 11) * SP_ + 15 + (row & 2047);
    uint16_t* orow = Hpad + drow * D_;
    orow[t] = f2bf((v0 - m) * rs * ln1s[t] + ln1b[t]);
    orow[t + 256] = f2bf((v1 - m) * rs * ln1s[t + 256] + ln1b[t + 256]);
    return;
  }
  if (bi == 25405) {  // ---- bucket (single block), groups padded to 128 ----
    __shared__ int cnt[G_], cur[G_];
    if (t < G_) cnt[t] = 0;
    __syncthreads();
    for (int i = t; i < N_; i += 256) atomicAdd(&cnt[gid[i]], 1);
    __syncthreads();
    if (t == 0) {
      int off = 0;
      for (int g = 0; g < G_; ++g) {
        poff[g] = off;
        cur[g] = off;
        off += (cnt[g] + 127) & ~127;
      }
      poff[G_] = off;
    }
    __syncthreads();
    for (int i = t; i < PADCAP_; i += 256) list[i] = N_;
    __syncthreads();
    for (int i = t; i < N_; i += 256) {
      int p = atomicAdd(&cur[gid[i]], 1);
      list[p] = i;
    }
    return;
  }
  if (bi >= 25344) {  // ---- zero-pad blocks ----
    int j4 = bi - 25344;
    uint16_t* dst;
    if (j4 < 60) {
      int b = j4 / 30, j = j4 % 30;
      int row = b * SP_ + (j < 15 ? j : 2048 + j);
      dst = Hpad + (size_t)row * D_;
    } else {
      dst = x2bf + (size_t)N_ * D_;
    }
    dst[t] = 0;
    dst[t + 256] = 0;
    return;
  }
  const float* src;
  uint16_t* dst;
  int R, C, r0, c0;
  if (bi < 7936) {
    int z = bi >> 8, tile = bi & 255;
    R = 512; C = 512;
    c0 = (tile & 15) * 32; r0 = (tile >> 4) * 32;
    src = ck + (size_t)z * 262144; dst = ckT + (size_t)z * 262144;
  } else if (bi < 8960) {
    int idx = bi - 7936, mat = idx >> 8, tile = idx & 255;
    R = 512; C = 512;
    c0 = (tile & 15) * 32; r0 = (tile >> 4) * 32;
    src = mat == 0 ? wq : (mat == 1 ? wk : (mat == 2 ? wv : wo));
    dst = mat == 3 ? woT : wqkvT + (size_t)mat * 262144;
  } else if (bi < 17152) {
    int idx = bi - 8960, z = idx >> 10, tile = idx & 1023;
    R = 512; C = 2048;
    c0 = (tile & 63) * 32; r0 = (tile >> 6) * 32;
    src = w1 + (size_t)z * 1048576; dst = w1T + (size_t)z * 1048576;
  } else {
    int idx = bi - 17152, z = idx >> 10, tile = idx & 1023;
    R = 2048; C = 512;
    c0 = (tile & 15) * 32; r0 = (tile >> 4) * 32;
    src = w2 + (size_t)z * 1048576; dst = w2T + (size_t)z * 1048576;
  }
  __shared__ float tile[32][33];
  int tc = t & 31, tr = t >> 5;
#pragma unroll
  for (int i = 0; i < 4; ++i) {
    int r = tr + i * 8;
    tile[r][tc] = src[(size_t)(r0 + r) * C + c0 + tc];
  }
  __syncthreads();
#pragma unroll
  for (int i = 0; i < 4; ++i) {
    int rr = tr + i * 8;
    dst[(size_t)(c0 + rr) * R + r0 + tc] = f2bf(tile[tc][rr]);
  }
}

// ---------------- conv: 256x256 block, 8 waves, faithful 4-phase schedule ---
__global__ __launch_bounds__(512) void conv_mfma_kernel(
    const uint16_t* __restrict__ Hpad, const uint16_t* __restrict__ ckT,
    uint16_t* __restrict__ Pout) {
  __shared__ __align__(16) uint16_t As[2][20480];
  __shared__ __align__(16) uint16_t Bs[2][16384];
  int bid = blockIdx.x;
  int ks = bid & 7, tmn = bid >> 3, tm = tmn & 15, tn = tmn >> 4;
  int t = threadIdx.x;
  int w = t >> 6, l = t & 63, l15 = l & 15, g = l >> 4;
  int wr = w >> 2, wc = w & 3;
  int row0 = tm * 256, b = row0 >> 11, s0 = row0 & 2047;
  int kb = ks * 4, ntap = (ks == 7) ? 3 : 4;
  const uint16_t* Abase = Hpad + (size_t)(b * SP_ + s0 + kb) * D_;
  int r8 = t >> 3, clog = (t & 7) ^ (r8 & 7);
  int ubase = (t & ~63) * 8;
  f32x4 acc[8][4] = {};

  auto stageA = [&](int d0, int buf) {
#pragma unroll
    for (int pi = 0; pi < 5; ++pi)
      GLOAD_LDS16(Abase + (size_t)(pi * 64 + r8) * D_ + d0 + clog * 8,
                  As[buf] + pi * 4096 + ubase);
  };
  auto stageB = [&](int k, int d0, int buf) {
    const uint16_t* Bk = ckT + (size_t)k * D_ * D_ + (size_t)(tn * 256) * D_;
#pragma unroll
    for (int pi = 0; pi < 4; ++pi)
      GLOAD_LDS16(Bk + (size_t)(pi * 64 + r8) * D_ + d0 + clog * 8,
                  Bs[buf] + pi * 4096 + ubase);
  };

  stageA(0, 0);
  stageB(kb, 0, 0);
  VMCNT(0);
  BARRIER; MEMBAR;

  int acur = 0, bcur = 0;
  for (int di = 0; di < 8; ++di) {
    int d0 = di * 64;
    for (int i = 0; i < ntap; ++i) {
      const char* Ac = (const char*)As[acur];
      const char* Bc = (const char*)Bs[bcur];
      bf16x8 a[4], bb[4];
      auto rdA = [&](int kkq, int mh) {
        int cA = (((kkq << 2) | g) ^ ((i + l15) & 7)) << 4;
#pragma unroll
        for (int mi = 0; mi < 4; ++mi)
          a[mi] = *(const bf16x8*)(Ac + (i + wr * 128 + (mh * 4 + mi) * 16 + l15) * 128 + cA);
      };
      auto rdB = [&](int kkq) {
        int cB = (((kkq << 2) | g) ^ (l15 & 7)) << 4;
#pragma unroll
        for (int n = 0; n < 4; ++n)
          bb[n] = *(const bf16x8*)(Bc + (wc * 64 + n * 16 + l15) * 128 + cB);
      };
      auto mma = [&](int mh) {
        PRIO1;
#pragma unroll
        for (int mi = 0; mi < 4; ++mi)
#pragma unroll
          for (int n = 0; n < 4; ++n)
            acc[mh * 4 + mi][n] = __builtin_amdgcn_mfma_f32_16x16x32_bf16(
                a[mi], bb[n], acc[mh * 4 + mi][n], 0, 0, 0);
        PRIO0;
      };
      // ---- phase 0: rd (mh0,kk0) pre-barrier, stage issue, barrier, MFMA --
      rdA(0, 0); rdB(0);
      MEMBAR;
      if (i + 1 < ntap) {
        stageB(kb + i + 1, d0, bcur ^ 1);
      } else if (di + 1 < 8) {
        stageA(d0 + 64, acur ^ 1);
        stageB(kb, d0 + 64, bcur ^ 1);
      }
      BARRIER;
      mma(0);
      MEMBAR; BARRIER;
      // ---- phase 1: (mh1,kk0), reuse bb ----
      rdA(0, 1);
      MEMBAR;
      BARRIER;
      mma(1);
      MEMBAR; BARRIER;
      // ---- phase 2: (mh0,kk1) ----
      rdA(1, 0); rdB(1);
      MEMBAR;
      BARRIER;
      mma(0);
      MEMBAR; BARRIER;
      // ---- phase 3: (mh1,kk1) + vmcnt for next tap's buffers ----
      rdA(1, 1);
      MEMBAR;
      VMCNT(0);
      BARRIER;
      mma(1);
      MEMBAR; BARRIER;
      bcur ^= 1;
    }
    acur ^= 1;
  }
  uint16_t* P = Pout + (size_t)ks * N_ * D_;
#pragma unroll
  for (int m = 0; m < 8; ++m) {
    int r = row0 + wr * 128 + m * 16 + g * 4;
#pragma unroll
    for (int n = 0; n < 4; ++n) {
      int c = tn * 256 + wc * 64 + n * 16 + l15;
#pragma unroll
      for (int j = 0; j < 4; ++j)
        P[(size_t)(r + j) * D_ + c] = f2bf(acc[m][n][j]);
    }
  }
}

// -------- conv epilogue + LN2 fused: one wave per token row ------------------
__global__ __launch_bounds__(256) void epi_ln_kernel(
    const uint16_t* __restrict__ P, const float* __restrict__ cb,
    const float* __restrict__ xres, const float* __restrict__ ln2s,
    const float* __restrict__ ln2b, float* __restrict__ x1,
    uint16_t* __restrict__ ln2bf) {
  int t = threadIdx.x;
  int row = blockIdx.x * 4 + (t >> 6);
  int l = t & 63, d0 = l * 8;
  size_t base = (size_t)row * D_ + d0;
  float v[8] = {};
#pragma unroll
  for (int q = 0; q < 8; ++q) {
    u16x8 pv = *(const u16x8*)(P + (size_t)q * N_ * D_ + base);
#pragma unroll
    for (int j = 0; j < 8; ++j) v[j] += bf2f(pv[j]);
  }
  float s = 0.f, sq = 0.f;
#pragma unroll
  for (int j = 0; j < 8; ++j) {
    float xv = xres[base + j];
    float vv = gelu_f(v[j] + cb[d0 + j]) + xv;
    v[j] = vv;
    s += vv;
    sq += vv * vv;
  }
  float4 o0 = {v[0], v[1], v[2], v[3]};
  float4 o1 = {v[4], v[5], v[6], v[7]};
  *(float4*)(x1 + base) = o0;
  *(float4*)(x1 + base + 4) = o1;
  for (int o = 1; o < 64; o <<= 1) {
    s += __shfl_xor(s, o);
    sq += __shfl_xor(sq, o);
  }
  float m = s / D_;
  float rs = rsqrtf(sq / D_ - m * m + EPS_);
  u16x8 ob;
#pragma unroll
  for (int j = 0; j < 8; ++j)
    ob[j] = f2bf((v[j] - m) * rs * ln2s[d0 + j] + ln2b[d0 + j]);
  *(u16x8*)(ln2bf + base) = ob;
}

// ------- fused QKV GEMM -> bf16 Q(scaled log2e/8), K row-major, V^T ---------
__global__ __launch_bounds__(256) void gemm_qkv_kernel(
    const uint16_t* __restrict__ A, const uint16_t* __restrict__ BT,
    const float* __restrict__ bq, const float* __restrict__ bk,
    const float* __restrict__ bv, uint16_t* __restrict__ Qb,
    uint16_t* __restrict__ Kb, uint16_t* __restrict__ VT) {
  __shared__ __align__(16) uint16_t As[2][8192], Bs[2][8192];
  int tm = blockIdx.x, tn = blockIdx.y;
  int t = threadIdx.x;
  int w = t >> 6, l = t & 63, l15 = l & 15, g = l >> 4;
  int wr = w >> 1, wc = w & 1;
  int row0 = tm * 128;
  f32x4 acc[4][4] = {};
  gemm_k_dbuf64<8>(A + (size_t)row0 * D_, D_, BT + (size_t)(tn * 128) * D_, D_,
                   t, wr, wc, l15, g, As, Bs, acc);
  int sel = tn >> 2, col0 = (tn & 3) * 128;
  if (sel < 2) {
    uint16_t* dst = sel == 0 ? Qb : Kb;
    const float* bias = sel == 0 ? bq : bk;
    float scl = sel == 0 ? 0.18033688f : 1.0f;  // (1/8) * log2(e) for exp2 softmax
#pragma unroll
    for (int m = 0; m < 4; ++m) {
      int r = row0 + wr * 64 + m * 16 + g * 4;
#pragma unroll
      for (int n = 0; n < 4; ++n) {
        int c = col0 + wc * 64 + n * 16 + l15;
#pragma unroll
        for (int j = 0; j < 4; ++j)
          dst[(size_t)(r + j) * D_ + c] = f2bf((acc[m][n][j] + bias[c]) * scl);
      }
    }
  } else {
    // V: store transposed [b][h][d][s] for direct attn staging
#pragma unroll
    for (int m = 0; m < 4; ++m) {
      int tb = row0 + wr * 64 + m * 16 + g * 4;
      int b = tb >> 11, s = tb & 2047;
#pragma unroll
      for (int n = 0; n < 4; ++n) {
        int c = col0 + wc * 64 + n * 16 + l15;
        int hh = c >> 6, d = c & 63;
        u16x4 pack;
#pragma unroll
        for (int j = 0; j < 4; ++j) pack[j] = f2bf(acc[m][n][j] + bv[c]);
        *(u16x4*)(VT + ((size_t)((b * H_ + hh) * HD_ + d) * S_ + s)) = pack;
      }
    }
  }
}

// ---------------- WO GEMM + bias + residual -> out (f32) + x2 (bf16) --------
__global__ __launch_bounds__(256) void gemm_wo_kernel(
    const uint16_t* __restrict__ A, const uint16_t* __restrict__ BT,
    const float* __restrict__ bo, const float* __restrict__ res,
    float* __restrict__ out, uint16_t* __restrict__ x2bf) {
  __shared__ __align__(16) uint16_t As[2][8192], Bs[2][8192];
  int tm = blockIdx.x, tn = blockIdx.y;
  int t = threadIdx.x;
  int w = t >> 6, l = t & 63, l15 = l & 15, g = l >> 4;
  int wr = w >> 1, wc = w & 1;
  int row0 = tm * 128;
  f32x4 acc[4][4] = {};
  gemm_k_dbuf64<8>(A + (size_t)row0 * D_, D_, BT + (size_t)(tn * 128) * D_, D_,
                   t, wr, wc, l15, g, As, Bs, acc);
#pragma unroll
  for (int m = 0; m < 4; ++m) {
    int r = row0 + wr * 64 + m * 16 + g * 4;
#pragma unroll
    for (int n = 0; n < 4; ++n) {
      int c = tn * 128 + wc * 64 + n * 16 + l15;
#pragma unroll
      for (int j = 0; j < 4; ++j) {
        float v = acc[m][n][j] + bo[c] + res[(size_t)(r + j) * D_ + c];
        out[(size_t)(r + j) * D_ + c] = v;
        x2bf[(size_t)(r + j) * D_ + c] = f2bf(v);
      }
    }
  }
}

// ------- MFMA flash attention: 128 q x 128 k tiles, 8 waves, defer-max ------
__global__ __launch_bounds__(512) void attn_mfma_kernel(
    const uint16_t* __restrict__ Qbf, const uint16_t* __restrict__ Kbf,
    const uint16_t* __restrict__ VT, uint16_t* __restrict__ obf) {
  __shared__ __align__(16) uint16_t Ks[2][8192];   // [128 key][64 d] swz
  __shared__ __align__(16) uint16_t Vt[2][8192];   // [64 d][128 k] swz
  __shared__ __align__(16) uint16_t Plds[16384];   // 8 waves x [16 q][128 k]
  int bid = blockIdx.x;
  int swz = (bid & 7) * 32 + (bid >> 3);   // XCD-contiguous (b,h) groups
  int qt = swz & 15, h = (swz >> 4) & 7, b = swz >> 7;
  int t = threadIdx.x, w = t >> 6, l = t & 63;
  int l15 = l & 15, g = l >> 4;
  int qbase = b * S_ + qt * 128;
  bf16x8 qb_[2];
  {
    const uint16_t* qp = Qbf + (size_t)(qbase + w * 16 + l15) * D_ + h * HD_;
#pragma unroll
    for (int ks = 0; ks < 2; ++ks)
      qb_[ks] = *(const bf16x8*)(qp + ks * 32 + g * 8);
  }
  const uint16_t* Kbase = Kbf + (size_t)(b * S_) * D_ + h * HD_;
  const uint16_t* Vbase = VT + (size_t)((b * H_ + h) * HD_) * S_;
  int rk0 = t >> 3, rk1 = 64 + (t >> 3), pk = t & 7;
  int rv0 = t >> 4, rv1 = 32 + (t >> 4), pv = t & 15;
  int ck0 = (pk ^ (rk0 & 7)) << 4, ck1 = (pk ^ (rk1 & 7)) << 4;
  int cv0 = (pv ^ (rv0 & 7)) << 4, cv1 = (pv ^ (rv1 & 7)) << 4;
  int ldst0 = (t & ~63) << 4, ldst1 = (512 + (t & ~63)) << 4;

  auto stage_kv = [&](int kt, int buf) {
    const uint16_t* Kp = Kbase + (size_t)(kt * 128) * D_;
    const uint16_t* Vp = Vbase + kt * 128;
    GLOAD_LDS16((const char*)(Kp + (size_t)rk0 * D_) + ck0, (char*)Ks[buf] + ldst0);
    GLOAD_LDS16((const char*)(Kp + (size_t)rk1 * D_) + ck1, (char*)Ks[buf] + ldst1);
    GLOAD_LDS16((const char*)(Vp + (size_t)rv0 * S_) + cv0, (char*)Vt[buf] + ldst0);
    GLOAD_LDS16((const char*)(Vp + (size_t)rv1 * S_) + cv1, (char*)Vt[buf] + ldst1);
  };

  f32x4 acc_o[4] = {};
  float m_run = -INFINITY, l_run = 0.f;  // state for q = l15 of this wave
  char* Pw = (char*)Plds + w * 4096;
  int swl = (l15 & 7) << 4;

  stage_kv(0, 0);
  int cur = 0;
  for (int kt = 0; kt < S_ / 128; ++kt) {
    if (kt + 1 < S_ / 128) {
      stage_kv(kt + 1, cur ^ 1);
      VMCNT(4);
    } else {
      VMCNT(0);
    }
    BARRIER; MEMBAR;
    const char* KsC = (const char*)Ks[cur];
    const char* VtC = (const char*)Vt[cur];
    f32x4 accs[8] = {};
#pragma unroll
    for (int ks = 0; ks < 2; ++ks) {
#pragma unroll
      for (int m = 0; m < 8; ++m) {
        int row = m * 16 + l15;
        bf16x8 kf = *(const bf16x8*)(KsC +
                        (row * 128 + ((ks * 64 + g * 16) ^ ((row & 7) << 4))));
        PRIO1;
        accs[m] = __builtin_amdgcn_mfma_f32_16x16x32_bf16(kf, qb_[ks], accs[m], 0, 0, 0);
        PRIO0;
      }
    }
    float mx = accs[0][0];
#pragma unroll
    for (int m = 0; m < 8; ++m)
#pragma unroll
      for (int j = 0; j < 4; ++j) mx = fmaxf(mx, accs[m][j]);
    mx = fmaxf(mx, __shfl_xor(mx, 16));
    mx = fmaxf(mx, __shfl_xor(mx, 32));
    if (!__all(mx <= m_run + 8.f)) {
      float mnew = fmaxf(m_run, mx);
      float corr = exp2f(m_run - mnew);
      m_run = mnew;
      l_run *= corr;
      float cj[4];
#pragma unroll
      for (int j = 0; j < 4; ++j) cj[j] = __shfl(corr, g * 4 + j);
#pragma unroll
      for (int n = 0; n < 4; ++n)
#pragma unroll
        for (int j = 0; j < 4; ++j) acc_o[n][j] *= cj[j];
    }
    float sum = 0.f;
#pragma unroll
    for (int m = 0; m < 8; ++m) {
      float p0 = exp2f(accs[m][0] - m_run);
      float p1 = exp2f(accs[m][1] - m_run);
      float p2 = exp2f(accs[m][2] - m_run);
      float p3 = exp2f(accs[m][3] - m_run);
      sum += (p0 + p1) + (p2 + p3);
      uint2 pk2;
      pk2.x = (uint32_t)f2bf(p0) | ((uint32_t)f2bf(p1) << 16);
      pk2.y = (uint32_t)f2bf(p2) | ((uint32_t)f2bf(p3) << 16);
      *(uint2*)(Pw + (l15 * 256 + ((m * 32 + g * 8) ^ swl))) = pk2;
    }
    sum += __shfl_xor(sum, 16);
    sum += __shfl_xor(sum, 32);
    l_run += sum;
#pragma unroll
    for (int s = 0; s < 4; ++s) {
      bf16x8 pa = *(const bf16x8*)(Pw + (l15 * 256 + ((s * 64 + g * 16) ^ swl)));
#pragma unroll
      for (int n = 0; n < 4; ++n) {
        int d = n * 16 + l15;
        bf16x8 vb = *(const bf16x8*)(VtC +
                        (d * 256 + ((s * 64 + g * 16) ^ ((d & 7) << 4))));
        PRIO1;
        acc_o[n] = __builtin_amdgcn_mfma_f32_16x16x32_bf16(pa, vb, acc_o[n], 0, 0, 0);
        PRIO0;
      }
    }
    MEMBAR; BARRIER;
    cur ^= 1;
  }
#pragma unroll
  for (int j = 0; j < 4; ++j) {
    float lr = __shfl(l_run, g * 4 + j);
    float inv = 1.f / lr;
    uint16_t* op = obf + (size_t)(qbase + w * 16 + g * 4 + j) * D_ + h * HD_;
#pragma unroll
    for (int n = 0; n < 4; ++n)
      op[n * 16 + l15] = f2bf(acc_o[n][j] * inv);
  }
}

// ------- MoE FF1: XCD-grouped weight columns (B-panel L2 locality) ----------
// 1-D grid 1152; swz=(bid&7)*144+(bid>>3): each XCD owns 4 (tn,e) weight
// columns x all 36 tm -> each w1T B-panel lives in exactly one XCD's L2.
__global__ __launch_bounds__(256) void ff1_mfma_kernel(
    const uint16_t* __restrict__ X, const uint16_t* __restrict__ w1T,
    const float* __restrict__ b1, const int* __restrict__ list,
    const int* __restrict__ poff, uint16_t* __restrict__ hid) {
  __shared__ __align__(16) uint16_t As[2][8192], Bs[2][8192];
  int bid = blockIdx.x;
  int swz = (bid & 7) * 144 + (bid >> 3);
  int col = swz / 36, tm = swz - col * 36;
  int tn = col & 15, e = col >> 4;
  int slot0 = tm * 128;
  if (slot0 >= poff[G_]) return;
  int g_ = 0;
#pragma unroll
  for (int gg = 1; gg < G_; ++gg) g_ += (slot0 >= poff[gg]);
  int t = threadIdx.x;
  int w = t >> 6, l = t & 63, l15 = l & 15, g = l >> 4;
  int wr = w >> 1, wc = w & 1;
  int r8 = t >> 3, clog = (t & 7) ^ (r8 & 7);
  int ubase = (t & ~63) * 8;
  int tok[4];
#pragma unroll
  for (int pi = 0; pi < 4; ++pi) tok[pi] = list[slot0 + pi * 32 + r8];
  const uint16_t* Bb = w1T + ((size_t)(g_ * E_ + e) * FF_ + tn * 128) * D_;
  f32x4 acc[4][4] = {};
  auto stage = [&](int k0, int buf) {
#pragma unroll
    for (int pi = 0; pi < 4; ++pi) {
      GLOAD_LDS16(X + (size_t)tok[pi] * D_ + k0 + clog * 8, As[buf] + pi * 2048 + ubase);
      GLOAD_LDS16(Bb + (size_t)(pi * 32 + r8) * D_ + k0 + clog * 8,
                  Bs[buf] + pi * 2048 + ubase);
    }
  };
  stage(0, 0);
  int cur = 0;
  for (int ki = 0; ki < 8; ++ki) {
    if (ki + 1 < 8) {
      stage((ki + 1) * 64, cur ^ 1);
      VMCNT(8);
    } else {
      VMCNT(0);
    }
    BARRIER; MEMBAR;
    kstep_swz((const char*)As[cur], (const char*)Bs[cur], wr, wc, l15, g, acc);
    MEMBAR; BARRIER;
    cur ^= 1;
  }
  const float* bias = b1 + (size_t)(g_ * E_ + e) * FF_;
  uint16_t* hidE = hid + (size_t)e * PADCAP_ * FF_;
#pragma unroll
  for (int m = 0; m < 4; ++m) {
    int r = slot0 + wr * 64 + m * 16 + g * 4;
#pragma unroll
    for (int n = 0; n < 4; ++n) {
      int c = tn * 128 + wc * 64 + n * 16 + l15;
#pragma unroll
      for (int j = 0; j < 4; ++j)
        hidE[(size_t)(r + j) * FF_ + c] = f2bf(gelu_f(acc[m][n][j] + bias[c]));
    }
  }
}

// ------- MoE FF2: 64x128 tile, XCD-grouped A-panel sharers, atomic ----------
// 1-D grid 576; swz=(bid&7)*72+(bid>>3) gives each XCD a contiguous chunk of
// tm in [9x,9x+9) x all 8 (tn,e) -> the 8 blocks sharing an A(hid) panel are
// co-resident on one XCD, so A K-slices are HBM-fetched once and L2-hit 7x.
__global__ __launch_bounds__(256) void ff2_mfma_kernel(
    const uint16_t* __restrict__ hid, const uint16_t* __restrict__ w2T,
    const float* __restrict__ b2, const int* __restrict__ list,
    const int* __restrict__ poff, float* __restrict__ out) {
  __shared__ __align__(16) uint16_t As[2][4096];   // 64 x 64k swizzled
  __shared__ __align__(16) uint16_t Bs[2][8192];   // 128 x 64k swizzled
  int bid = blockIdx.x;
  int swz = (bid & 7) * 72 + (bid >> 3);
  int tm = swz >> 3, tn = swz & 3, e = (swz >> 2) & 1;
  int slot0 = tm * 64;
  if (slot0 >= poff[G_]) return;
  int g_ = 0;
#pragma unroll
  for (int gg = 1; gg < G_; ++gg) g_ += (slot0 >= poff[gg]);
  int t = threadIdx.x;
  int w = t >> 6, l = t & 63, l15 = l & 15, g = l >> 4;
  int wr = w >> 1, wc = w & 1;
  int r8 = t >> 3, clog = (t & 7) ^ (r8 & 7);
  int ubase = (t & ~63) * 8;
  const uint16_t* Ab = hid + ((size_t)e * PADCAP_ + slot0) * FF_;
  const uint16_t* Bb = w2T + (size_t)(g_ * E_ + e) * D_ * FF_ + (size_t)(tn * 128) * FF_;
  f32x4 acc[2][4] = {};
  auto stage = [&](int k0, int buf) {
#pragma unroll
    for (int pi = 0; pi < 2; ++pi)
      GLOAD_LDS16(Ab + (size_t)(pi * 32 + r8) * FF_ + k0 + clog * 8,
                  As[buf] + pi * 2048 + ubase);
#pragma unroll
    for (int pi = 0; pi < 4; ++pi)
      GLOAD_LDS16(Bb + (size_t)(pi * 32 + r8) * FF_ + k0 + clog * 8,
                  Bs[buf] + pi * 2048 + ubase);
  };
  stage(0, 0);
  int cur = 0;
  for (int ki = 0; ki < 32; ++ki) {
    if (ki + 1 < 32) {
      stage((ki + 1) * 64, cur ^ 1);
      VMCNT(6);
    } else {
      VMCNT(0);
    }
    BARRIER; MEMBAR;
    const char* Ac = (const char*)As[cur];
    const char* Bc = (const char*)Bs[cur];
#pragma unroll
    for (int ks = 0; ks < 2; ++ks) {
      int co = (((ks << 2) | g) ^ (l15 & 7)) << 4;
      bf16x8 a[2], b[4];
#pragma unroll
      for (int m = 0; m < 2; ++m)
        a[m] = *(const bf16x8*)(Ac + (wr * 32 + m * 16 + l15) * 128 + co);
#pragma unroll
      for (int n = 0; n < 4; ++n)
        b[n] = *(const bf16x8*)(Bc + (wc * 64 + n * 16 + l15) * 128 + co);
      PRIO1;
#pragma unroll
      for (int m = 0; m < 2; ++m)
#pragma unroll
        for (int n = 0; n < 4; ++n)
          acc[m][n] = __builtin_amdgcn_mfma_f32_16x16x32_bf16(a[m], b[n], acc[m][n], 0, 0, 0);
      PRIO0;
    }
    MEMBAR; BARRIER;
    cur ^= 1;
  }
  const float* be = b2 + (size_t)(g_ * E_ + e) * D_;
#pragma unroll
  for (int m = 0; m < 2; ++m) {
    int rbase = slot0 + wr * 32 + m * 16 + g * 4;
#pragma unroll
    for (int j = 0; j < 4; ++j) {
      int tok = list[rbase + j];
      if (tok >= N_) continue;
#pragma unroll
      for (int n = 0; n < 4; ++n) {
        int c = tn * 128 + wc * 64 + n * 16 + l15;
        atomicAdd(&out[(size_t)tok * D_ + c], 0.5f * (acc[m][n][j] + be[c]));
      }
    }
  }
}

}  // namespace

extern "C" void kernel_launch(void* const* d_in, const int* in_sizes, int n_in,
                              void* d_out, int out_size, void* d_ws, size_t ws_size,
                              hipStream_t stream) {
  const float* x = (const float*)d_in[0];
  const int* gid = (const int*)d_in[1];
  const float* ln1s = (const float*)d_in[2];
  const float* ln1b = (const float*)d_in[3];
  const float* ck = (const float*)d_in[4];
  const float* cb = (const float*)d_in[5];
  const float* ln2s = (const float*)d_in[6];
  const float* ln2b = (const float*)d_in[7];
  const float* wq = (const float*)d_in[8];
  const float* bq = (const float*)d_in[9];
  const float* wk = (const float*)d_in[10];
  const float* bk = (const float*)d_in[11];
  const float* wv = (const float*)d_in[12];
  const float* bv = (const float*)d_in[13];
  const float* wo = (const float*)d_in[14];
  const float* bo = (const float*)d_in[15];
  const float* w1 = (const float*)d_in[16];
  const float* b1 = (const float*)d_in[17];
  const float* w2 = (const float*)d_in[18];
  const float* b2 = (const float*)d_in[19];
  float* out = (float*)d_out;

  char* ws = (char*)d_ws;
  // Region A (38 MiB), time-multiplexed:
  //  conv:  P[8] bf16 partials (32 MiB) | ln2bf at +32MiB (4 MiB)
  //  attn:  Qbf(0) | Kbf(+4) | VT(+8) | obf(+12)
  //  moe:   hidbf (2 x 4608 x 2048 bf16 = 36 MiB)
  char* A = ws;
  uint16_t* P = (uint16_t*)A;
  uint16_t* ln2bf = (uint16_t*)(A + (32ull << 20));
  uint16_t* Qbf = (uint16_t*)A;
  uint16_t* Kbf = (uint16_t*)(A + (4ull << 20));
  uint16_t* VT = (uint16_t*)(A + (8ull << 20));
  uint16_t* obf = (uint16_t*)(A + (12ull << 20));
  uint16_t* hidbf = (uint16_t*)A;

  float* x1 = (float*)(ws + (38ull << 20));
  uint16_t* Hpad = (uint16_t*)(ws + (46ull << 20));
  uint16_t* ckT = (uint16_t*)(ws + (51ull << 20));
  uint16_t* wqkvT = (uint16_t*)(ws + (67ull << 20));
  uint16_t* woT = (uint16_t*)(ws + (69ull << 20));
  uint16_t* w1T = (uint16_t*)(ws + (70ull << 20));
  uint16_t* w2T = (uint16_t*)(ws + (86ull << 20));
  uint16_t* x2bf = (uint16_t*)(ws + (102ull << 20));
  int* list = (int*)(ws + (107ull << 20));
  int* poff = list + PADCAP_;

  prep_kernel<<<29502, 256, 0, stream>>>(ck, wq, wk, wv, wo, w1, w2,
                                         ckT, wqkvT, woT, w1T, w2T, Hpad, x2bf,
                                         x, ln1s, ln1b, gid, list, poff);

  // conv sublayer (+ fused LN2)
  conv_mfma_kernel<<<256, 512, 0, stream>>>(Hpad, ckT, P);
  epi_ln_kernel<<<1024, 256, 0, stream>>>(P, cb, x, ln2s, ln2b, x1, ln2bf);

  // attention sublayer
  gemm_qkv_kernel<<<dim3(32, 12), 256, 0, stream>>>(ln2bf, wqkvT, bq, bk, bv, Qbf, Kbf, VT);
  attn_mfma_kernel<<<256, 512, 0, stream>>>(Qbf, Kbf, VT, obf);
  gemm_wo_kernel<<<dim3(32, 4), 256, 0, stream>>>(obf, woT, bo, x1, out, x2bf);

  // MoE sublayer
  ff1_mfma_kernel<<<1152, 256, 0, stream>>>(x2bf, w1T, b1, list, poff, hidbf);
  ff2_mfma_kernel<<<576, 256, 0, stream>>>(hidbf, w2T, b2, list, poff, out);
}